// Round 4
// baseline (576.629 us; speedup 1.0000x reference)
//
#include <hip/hip_runtime.h>

typedef unsigned short u16;
typedef float f32x4 __attribute__((ext_vector_type(4)));
typedef __bf16 bf16x8 __attribute__((ext_vector_type(8)));
typedef u16 u16x8 __attribute__((ext_vector_type(8)));

static __device__ __forceinline__ u16 f2bf(float f) {
  union { float f; unsigned u; } v; v.f = f;
  unsigned r = v.u + 0x7fffu + ((v.u >> 16) & 1u);  // RNE
  return (u16)(r >> 16);
}
static __device__ __forceinline__ float bf2f(u16 x) {
  union { unsigned u; float f; } v; v.u = (unsigned)x << 16; return v.f;
}

static __device__ __forceinline__ f32x4 mfma16(u16x8 a, u16x8 b, f32x4 c) {
  return __builtin_amdgcn_mfma_f32_16x16x32_bf16(
      __builtin_bit_cast(bf16x8, a), __builtin_bit_cast(bf16x8, b), c, 0, 0, 0);
}

static __device__ __forceinline__ void load_lds16(const void* g, void* l) {
  __builtin_amdgcn_global_load_lds(
      (const __attribute__((address_space(1))) void*)g,
      (__attribute__((address_space(3))) void*)l, 16, 0, 0);
}

// ---------------- elementwise f32 -> bf16 ----------------
__global__ void cvt_f32_bf16(const float* __restrict__ in, u16* __restrict__ out, int n4) {
  int i = blockIdx.x * blockDim.x + threadIdx.x;
  if (i >= n4) return;
  float4 v = ((const float4*)in)[i];
  ushort4 o;
  o.x = f2bf(v.x); o.y = f2bf(v.y); o.z = f2bf(v.z); o.w = f2bf(v.w);
  ((ushort4*)out)[i] = o;
}

// ---------------- transpose + convert: W[K][N] f32 -> Wt[N][K] bf16 ----------------
__global__ __launch_bounds__(256)
void transpose_cvt(const float* __restrict__ W, u16* __restrict__ Wt, int K, int N) {
  __shared__ float tile[32][33];
  int tx = threadIdx.x & 31, ty = threadIdx.x >> 5;
  int k0 = blockIdx.x * 32, n0 = blockIdx.y * 32;
  #pragma unroll
  for (int i = ty; i < 32; i += 8)
    tile[i][tx] = W[(size_t)(k0 + i) * N + (n0 + tx)];
  __syncthreads();
  #pragma unroll
  for (int i = ty; i < 32; i += 8)
    Wt[(size_t)(n0 + i) * K + (k0 + tx)] = f2bf(tile[tx][i]);
}

// ---------------- V transpose: qkv V cols [s][hk*128+d] -> vt[hk][d][s] ----------------
__global__ __launch_bounds__(256)
void vtrans_k(const u16* __restrict__ qkv, u16* __restrict__ vt) {
  __shared__ u16 tile[32][33];
  int tx = threadIdx.x & 31, ty = threadIdx.x >> 5;
  int s0 = blockIdx.x * 32;          // 64 tiles over s
  int d0 = (blockIdx.y & 3) * 32;    // 4 tiles over d
  int hk = blockIdx.y >> 2;          // 8 kv heads
  const u16* src = qkv + 5120 + (size_t)hk * 128;
  #pragma unroll
  for (int i = ty; i < 32; i += 8)
    tile[i][tx] = src[(size_t)(s0 + i) * 6144 + d0 + tx];
  __syncthreads();
  u16* dst = vt + (size_t)hk * 128 * 2048;
  #pragma unroll
  for (int i = ty; i < 32; i += 8)
    dst[(size_t)(d0 + i) * 2048 + s0 + tx] = tile[tx][i];
}

// ---------------- RoPE cos/sin table: [L][64] float2 ----------------
__global__ void rope_table_k(float2* __restrict__ tab, const int* __restrict__ start, int L) {
  int i = blockIdx.x * blockDim.x + threadIdx.x;
  if (i >= L * 64) return;
  int p = i >> 6, j = i & 63;
  float inv = powf(10000.0f, -(float)j / 64.0f);
  float ang = (float)(p + start[0]) * inv;
  tab[i] = make_float2(cosf(ang), sinf(ang));
}

// ---------------- RoPE apply (bf16 in, strided) -> bf16 [L][H][128], * scale ----------------
__global__ void rope_apply_b(const u16* __restrict__ in, int istride, int icol,
                             u16* __restrict__ outp, const float2* __restrict__ tab,
                             int total, int H, float scale) {
  int i = blockIdx.x * blockDim.x + threadIdx.x;  // total = L*H*8
  if (i >= total) return;
  int j8 = (i & 7) * 8;
  int h = (i >> 3) % H;
  int p = i / (8 * H);
  const u16* base = in + (size_t)p * istride + icol + h * 128;
  u16x8 a = *(const u16x8*)(base + j8);
  u16x8 b = *(const u16x8*)(base + j8 + 64);
  u16x8 o1, o2;
  #pragma unroll
  for (int e = 0; e < 8; e++) {
    float2 cs = tab[p * 64 + j8 + e];
    float av = bf2f(a[e]), bv = bf2f(b[e]);
    o1[e] = f2bf((av * cs.x - bv * cs.y) * scale);
    o2[e] = f2bf((av * cs.y + bv * cs.x) * scale);
  }
  u16* ob = outp + ((size_t)p * H + h) * 128 + j8;
  *(u16x8*)ob = o1;
  *(u16x8*)(ob + 64) = o2;
}

// ---------------- GEMM: C[M][N] = A[M][K](bf16) @ Bt[N][K](bf16) ----------------
template<bool OUT_BF16>
__global__ __launch_bounds__(256)
void gemm_bt(const u16* __restrict__ A, const u16* __restrict__ Bt,
             float* __restrict__ Cf, u16* __restrict__ Cb, int M, int N, int K) {
  __shared__ alignas(16) u16 As[128 * 32];
  __shared__ alignas(16) u16 Bs[128 * 32];
  const int tid = threadIdx.x;
  const int lane = tid & 63, wave = tid >> 6;
  const int ql = lane & 15, kg = lane >> 4;
  const int m0 = blockIdx.x * 128, n0 = blockIdx.y * 128;
  const int wm = (wave >> 1) * 64, wn = (wave & 1) * 64;

  f32x4 acc[4][4] = {};

  const int c0 = tid, c1 = 256 + tid;
  const int r0 = c0 >> 2, e0 = (c0 & 3) * 8;
  const int r1 = c1 >> 2, e1 = (c1 & 3) * 8;
  const u16* a0 = A + (size_t)(m0 + r0) * K + e0;
  const u16* a1 = A + (size_t)(m0 + r1) * K + e1;
  const u16* b0 = Bt + (size_t)(n0 + r0) * K + e0;
  const u16* b1 = Bt + (size_t)(n0 + r1) * K + e1;
  u16* lA0 = &As[c0 * 8]; u16* lA1 = &As[c1 * 8];
  u16* lB0 = &Bs[c0 * 8]; u16* lB1 = &Bs[c1 * 8];

  for (int k0 = 0; k0 < K; k0 += 32) {
    __syncthreads();
    load_lds16(a0 + k0, lA0);
    load_lds16(a1 + k0, lA1);
    load_lds16(b0 + k0, lB0);
    load_lds16(b1 + k0, lB1);
    __syncthreads();
    u16x8 af[4], bfr[4];
    #pragma unroll
    for (int mi = 0; mi < 4; mi++)
      af[mi] = *(const u16x8*)&As[(wm + mi * 16 + ql) * 32 + kg * 8];
    #pragma unroll
    for (int ni = 0; ni < 4; ni++)
      bfr[ni] = *(const u16x8*)&Bs[(wn + ni * 16 + ql) * 32 + kg * 8];
    #pragma unroll
    for (int mi = 0; mi < 4; mi++)
      #pragma unroll
      for (int ni = 0; ni < 4; ni++)
        acc[mi][ni] = mfma16(af[mi], bfr[ni], acc[mi][ni]);
  }

  #pragma unroll
  for (int mi = 0; mi < 4; mi++) {
    #pragma unroll
    for (int ni = 0; ni < 4; ni++) {
      int row = m0 + wm + mi * 16 + kg * 4;
      int col = n0 + wn + ni * 16 + ql;
      #pragma unroll
      for (int r = 0; r < 4; r++) {
        if constexpr (OUT_BF16)
          Cb[(size_t)(row + r) * N + col] = f2bf(acc[mi][ni][r]);
        else
          Cf[(size_t)(row + r) * N + col] = acc[mi][ni][r];
      }
    }
  }
}

// ---------------- flash attention, causal, GQA (g=4), BARRIER-FREE ----------------
// grid (16, 32 heads), 256 thr = 4 waves; block handles q-tiles {bx, 31-bx}.
// KVBLK=64. V pre-transposed in global (vt[hk][d][s]) -> PV B-fragments are
// per-lane contiguous b128 global loads; no LDS V staging, no __syncthreads.
// K and V fragments prefetched into regs (single-buffer, issued post-consume).
// LDS = wave-private Plds only. Swapped QK^T; exp2-domain softmax (Q
// pre-scaled by log2e/sqrt(d)); defer-max THR=11.5.
__global__ __launch_bounds__(256, 2)
void attn_k(const u16* __restrict__ qr, const u16* __restrict__ kr,
            const u16* __restrict__ vt, u16* __restrict__ out) {
  __shared__ alignas(16) u16 Plds[4][16][72];
  const int tid = threadIdx.x;
  const int lane = tid & 63, wave = tid >> 6;
  const int ql = lane & 15, kg = lane >> 4;
  const int h = blockIdx.y, hk = h >> 2;

  // K fragment base: kr[s][hk*128 + d], per-lane row s = ql (+16sb), d-slice kg*8
  const u16* kptr = kr + (size_t)hk * 128 + (size_t)ql * 1024 + kg * 8;
  // V fragment base: vt[hk][d][s]; lane: d = ql (+16db), s-slice kg*8
  const u16* vptr = vt + ((size_t)hk * 128 + ql) * 2048 + kg * 8;

  #pragma unroll 1
  for (int half_idx = 0; half_idx < 2; half_idx++) {
    const int tile = half_idx ? (31 - (int)blockIdx.x) : (int)blockIdx.x;
    const int q0 = tile * 64;
    const int qw = q0 + wave * 16;
    const int nsteps = tile + 1;

    u16x8 qf[4];
    const u16* qbase = qr + ((size_t)(qw + ql) * 32 + h) * 128;
    #pragma unroll
    for (int kk = 0; kk < 4; kk++)
      qf[kk] = *(const u16x8*)(qbase + kk * 32 + kg * 8);

    f32x4 acc[8] = {};
    float m_run = -3e38f, l_run = 0.f;

    // prologue: K and V fragments for step 0
    u16x8 kreg[4][4], vfrag[2][8];
    #pragma unroll
    for (int sb = 0; sb < 4; sb++)
      #pragma unroll
      for (int kk = 0; kk < 4; kk++)
        kreg[sb][kk] = *(const u16x8*)(kptr + (size_t)(sb * 16) * 1024 + kk * 32);
    #pragma unroll
    for (int hf = 0; hf < 2; hf++)
      #pragma unroll
      for (int db = 0; db < 8; db++)
        vfrag[hf][db] = *(const u16x8*)(vptr + (size_t)(db * 16) * 2048 + hf * 32);

    #pragma unroll 1
    for (int t = 0; t < nsteps; t++) {
      const int s0 = t * 64;
      // (1) QK^T from registers: D[s][q], A = K rows, B = Q
      f32x4 sc[4] = {};
      __builtin_amdgcn_s_setprio(1);
      #pragma unroll
      for (int sb = 0; sb < 4; sb++)
        #pragma unroll
        for (int kk = 0; kk < 4; kk++)
          sc[sb] = mfma16(kreg[sb][kk], qf[kk], sc[sb]);
      __builtin_amdgcn_s_setprio(0);
      // (2) prefetch K for step t+1 (WAR on kreg; lands during softmax+PV)
      if (t + 1 < nsteps) {
        #pragma unroll
        for (int sb = 0; sb < 4; sb++)
          #pragma unroll
          for (int kk = 0; kk < 4; kk++)
            kreg[sb][kk] = *(const u16x8*)(kptr + (size_t)((t + 1) * 64 + sb * 16) * 1024 + kk * 32);
      }
      // (3) online softmax, exp2 domain, defer-max; P overwrites sc in place
      const int qg = qw + ql;
      float mt = -3e38f;
      #pragma unroll
      for (int sb = 0; sb < 4; sb++)
        #pragma unroll
        for (int r = 0; r < 4; r++) {
          int s = s0 + sb * 16 + kg * 4 + r;
          float v = (s > qg) ? -3e38f : sc[sb][r];
          sc[sb][r] = v;
          mt = fmaxf(mt, v);
        }
      mt = fmaxf(mt, __shfl_xor(mt, 16, 64));
      mt = fmaxf(mt, __shfl_xor(mt, 32, 64));
      if (!__all(mt - m_run <= 11.5f)) {
        float m_new = fmaxf(m_run, mt);
        float fco = exp2f(m_run - m_new);
        float fr[4];
        #pragma unroll
        for (int r = 0; r < 4; r++) fr[r] = __shfl(fco, (lane & 48) | (kg * 4 + r), 64);
        #pragma unroll
        for (int db = 0; db < 8; db++)
          #pragma unroll
          for (int r = 0; r < 4; r++) acc[db][r] *= fr[r];
        l_run *= fco;
        m_run = m_new;
      }
      float rs = 0.f;
      #pragma unroll
      for (int sb = 0; sb < 4; sb++)
        #pragma unroll
        for (int r = 0; r < 4; r++) {
          float e = exp2f(sc[sb][r] - m_run);
          sc[sb][r] = e;
          rs += e;
        }
      rs += __shfl_xor(rs, 16, 64);
      rs += __shfl_xor(rs, 32, 64);
      l_run += rs;
      // (4) P -> wave-private LDS (transpose s<->q ownership); no block barrier
      #pragma unroll
      for (int sb = 0; sb < 4; sb++) {
        ushort4 pk;
        pk.x = f2bf(sc[sb][0]); pk.y = f2bf(sc[sb][1]);
        pk.z = f2bf(sc[sb][2]); pk.w = f2bf(sc[sb][3]);
        *(ushort4*)&Plds[wave][ql][sb * 16 + kg * 4] = pk;
      }
      // (5) PV: A = P[q][s], B = V^T fragments from regs
      __builtin_amdgcn_s_setprio(1);
      #pragma unroll
      for (int hf = 0; hf < 2; hf++) {
        u16x8 pf = *(const u16x8*)&Plds[wave][ql][hf * 32 + kg * 8];
        #pragma unroll
        for (int db = 0; db < 8; db++)
          acc[db] = mfma16(pf, vfrag[hf][db], acc[db]);
      }
      __builtin_amdgcn_s_setprio(0);
      // (6) prefetch V for step t+1 (lands during next QK+softmax)
      if (t + 1 < nsteps) {
        #pragma unroll
        for (int hf = 0; hf < 2; hf++)
          #pragma unroll
          for (int db = 0; db < 8; db++)
            vfrag[hf][db] = *(const u16x8*)(vptr + (size_t)(db * 16) * 2048 + (t + 1) * 64 + hf * 32);
      }
    }

    // epilogue for this q-tile
    float linv[4];
    #pragma unroll
    for (int r = 0; r < 4; r++)
      linv[r] = 1.f / __shfl(l_run, (lane & 48) | (kg * 4 + r), 64);
    #pragma unroll
    for (int db = 0; db < 8; db++) {
      int d = db * 16 + ql;
      #pragma unroll
      for (int r = 0; r < 4; r++) {
        int q = qw + kg * 4 + r;
        out[((size_t)q * 32 + h) * 128 + d] = f2bf(acc[db][r] * linv[r]);
      }
    }
  }
}

// ---------------- launcher ----------------
extern "C" void kernel_launch(void* const* d_in, const int* in_sizes, int n_in,
                              void* d_out, int out_size, void* d_ws, size_t ws_size,
                              hipStream_t stream) {
  const float* x  = (const float*)d_in[0];
  const float* Wq = (const float*)d_in[1];
  const float* Wk = (const float*)d_in[2];
  const float* Wv = (const float*)d_in[3];
  const float* Wo = (const float*)d_in[4];
  const int* start = (const int*)d_in[5];

  const int L = 2048, HID = 4096, NH = 32, NKV = 8;
  const int NQ = 4096, NKVD = 1024, NF = 6144;

  char* ws = (char*)d_ws;
  size_t off = 0;
  auto alloc = [&](size_t bytes) {
    void* p = ws + off;
    off += (bytes + 255) & ~(size_t)255;
    return p;
  };
  u16* x_b   = (u16*)alloc((size_t)L * HID * 2);
  // Wq_t, Wk_t, Wv_t MUST be contiguous (fused GEMM reads them as one
  // 6144-row Bt). Sizes are 256B-multiples so alloc() leaves no gaps.
  u16* Wq_t  = (u16*)alloc((size_t)NQ * HID * 2);
  u16* Wk_t  = (u16*)alloc((size_t)NKVD * HID * 2);
  u16* Wv_t  = (u16*)alloc((size_t)NKVD * HID * 2);
  u16* Wo_t  = (u16*)alloc((size_t)HID * NQ * 2);
  u16* q_r   = (u16*)alloc((size_t)L * NQ * 2);
  u16* k_r   = (u16*)alloc((size_t)L * NKVD * 2);
  u16* vt_b  = (u16*)alloc((size_t)NKV * 128 * L * 2);
  float2* tab = (float2*)alloc((size_t)L * 64 * sizeof(float2));
  // fused QKV output lives in d_out (25.2MB < 33.5MB); fully rewritten by the
  // final out-projection afterwards.
  u16* qkv_b  = (u16*)d_out;
  u16* attn_b = Wq_t;  // reuse Wq^T region after the fused GEMM

  const float qscale = 0.08838834764831845f * 1.4426950408889634f;  // 1/sqrt(128)*log2(e)

  // conversions / transposes / table
  cvt_f32_bf16<<<(L * HID / 4 + 255) / 256, 256, 0, stream>>>(x, x_b, L * HID / 4);
  transpose_cvt<<<dim3(HID / 32, NQ / 32), 256, 0, stream>>>(Wq, Wq_t, HID, NQ);
  transpose_cvt<<<dim3(HID / 32, NKVD / 32), 256, 0, stream>>>(Wk, Wk_t, HID, NKVD);
  transpose_cvt<<<dim3(HID / 32, NKVD / 32), 256, 0, stream>>>(Wv, Wv_t, HID, NKVD);
  transpose_cvt<<<dim3(NQ / 32, HID / 32), 256, 0, stream>>>(Wo, Wo_t, NQ, HID);
  rope_table_k<<<(L * 64 + 255) / 256, 256, 0, stream>>>(tab, start, L);

  // fused QKV projection: [2048][6144] bf16 into d_out scratch
  gemm_bt<true><<<dim3(L / 128, NF / 128), 256, 0, stream>>>(x_b, Wq_t, nullptr, qkv_b, L, NF, HID);

  // RoPE: Q (scaled, log2e folded) and K (unscaled), both bf16 in/out
  rope_apply_b<<<(L * NH * 8 + 255) / 256, 256, 0, stream>>>(qkv_b, NF, 0, q_r, tab, L * NH * 8, NH, qscale);
  rope_apply_b<<<(L * NKV * 8 + 255) / 256, 256, 0, stream>>>(qkv_b, NF, NQ, k_r, tab, L * NKV * 8, NKV, 1.0f);

  // V transpose to vt[hk][d][s]
  vtrans_k<<<dim3(L / 32, 32), 256, 0, stream>>>(qkv_b, vt_b);

  // attention (barrier-free)
  attn_k<<<dim3(16, NH), 256, 0, stream>>>(q_r, k_r, vt_b, attn_b);

  // output projection (rewrites all of d_out)
  gemm_bt<false><<<dim3(L / 128, HID / 128), 256, 0, stream>>>(attn_b, Wo_t, (float*)d_out, nullptr, L, HID, NQ);
}

// Round 5
// 418.973 us; speedup vs baseline: 1.3763x; 1.3763x over previous
//
#include <hip/hip_runtime.h>

typedef unsigned short u16;
typedef float f32x4 __attribute__((ext_vector_type(4)));
typedef __bf16 bf16x8 __attribute__((ext_vector_type(8)));
typedef u16 u16x8 __attribute__((ext_vector_type(8)));

static __device__ __forceinline__ u16 f2bf(float f) {
  union { float f; unsigned u; } v; v.f = f;
  unsigned r = v.u + 0x7fffu + ((v.u >> 16) & 1u);  // RNE
  return (u16)(r >> 16);
}
static __device__ __forceinline__ float bf2f(u16 x) {
  union { unsigned u; float f; } v; v.u = (unsigned)x << 16; return v.f;
}

static __device__ __forceinline__ f32x4 mfma16(u16x8 a, u16x8 b, f32x4 c) {
  return __builtin_amdgcn_mfma_f32_16x16x32_bf16(
      __builtin_bit_cast(bf16x8, a), __builtin_bit_cast(bf16x8, b), c, 0, 0, 0);
}

static __device__ __forceinline__ void load_lds16(const void* g, void* l) {
  __builtin_amdgcn_global_load_lds(
      (const __attribute__((address_space(1))) void*)g,
      (__attribute__((address_space(3))) void*)l, 16, 0, 0);
}

// ---------------- elementwise f32 -> bf16 ----------------
__global__ void cvt_f32_bf16(const float* __restrict__ in, u16* __restrict__ out, int n4) {
  int i = blockIdx.x * blockDim.x + threadIdx.x;
  if (i >= n4) return;
  float4 v = ((const float4*)in)[i];
  ushort4 o;
  o.x = f2bf(v.x); o.y = f2bf(v.y); o.z = f2bf(v.z); o.w = f2bf(v.w);
  ((ushort4*)out)[i] = o;
}

// ---------------- transpose + convert: W[K][N] f32 -> Wt[N][K] bf16 ----------------
__global__ __launch_bounds__(256)
void transpose_cvt(const float* __restrict__ W, u16* __restrict__ Wt, int K, int N) {
  __shared__ float tile[32][33];
  int tx = threadIdx.x & 31, ty = threadIdx.x >> 5;
  int k0 = blockIdx.x * 32, n0 = blockIdx.y * 32;
  #pragma unroll
  for (int i = ty; i < 32; i += 8)
    tile[i][tx] = W[(size_t)(k0 + i) * N + (n0 + tx)];
  __syncthreads();
  #pragma unroll
  for (int i = ty; i < 32; i += 8)
    Wt[(size_t)(n0 + i) * K + (k0 + tx)] = f2bf(tile[tx][i]);
}

// ---------------- RoPE cos/sin table: [L][64] float2 ----------------
__global__ void rope_table_k(float2* __restrict__ tab, const int* __restrict__ start, int L) {
  int i = blockIdx.x * blockDim.x + threadIdx.x;
  if (i >= L * 64) return;
  int p = i >> 6, j = i & 63;
  float inv = powf(10000.0f, -(float)j / 64.0f);
  float ang = (float)(p + start[0]) * inv;
  tab[i] = make_float2(cosf(ang), sinf(ang));
}

// ---------------- RoPE apply (bf16 in, strided) -> bf16 [L][H][128], * scale ----------
// swz!=0: store 16B-chunk c of row p at chunk c^(p&7) within each 64-elem half
// (pre-swizzle for conflict-free LDS reads after linear global_load_lds staging).
__global__ void rope_apply_b(const u16* __restrict__ in, int istride, int icol,
                             u16* __restrict__ outp, const float2* __restrict__ tab,
                             int total, int H, float scale, int swz) {
  int i = blockIdx.x * blockDim.x + threadIdx.x;  // total = L*H*8
  if (i >= total) return;
  int j8 = (i & 7) * 8;
  int h = (i >> 3) % H;
  int p = i / (8 * H);
  const u16* base = in + (size_t)p * istride + icol + h * 128;
  u16x8 a = *(const u16x8*)(base + j8);
  u16x8 b = *(const u16x8*)(base + j8 + 64);
  u16x8 o1, o2;
  #pragma unroll
  for (int e = 0; e < 8; e++) {
    float2 cs = tab[p * 64 + j8 + e];
    float av = bf2f(a[e]), bv = bf2f(b[e]);
    o1[e] = f2bf((av * cs.x - bv * cs.y) * scale);
    o2[e] = f2bf((av * cs.y + bv * cs.x) * scale);
  }
  int c1 = i & 7;
  int cs1 = swz ? (c1 ^ (p & 7)) : c1;
  u16* ob = outp + ((size_t)p * H + h) * 128 + cs1 * 8;
  *(u16x8*)ob = o1;
  *(u16x8*)(ob + 64) = o2;   // chunk c1+8 -> swizzled (c1+8)^(p&7) = cs1+8
}

// ---------------- GEMM: C[M][N] = A[M][K](bf16) @ Bt[N][K](bf16) ----------------
template<bool OUT_BF16>
__global__ __launch_bounds__(256)
void gemm_bt(const u16* __restrict__ A, const u16* __restrict__ Bt,
             float* __restrict__ Cf, u16* __restrict__ Cb, int M, int N, int K) {
  __shared__ alignas(16) u16 As[128 * 32];
  __shared__ alignas(16) u16 Bs[128 * 32];
  const int tid = threadIdx.x;
  const int lane = tid & 63, wave = tid >> 6;
  const int ql = lane & 15, kg = lane >> 4;
  const int m0 = blockIdx.x * 128, n0 = blockIdx.y * 128;
  const int wm = (wave >> 1) * 64, wn = (wave & 1) * 64;

  f32x4 acc[4][4] = {};

  const int c0 = tid, c1 = 256 + tid;
  const int r0 = c0 >> 2, e0 = (c0 & 3) * 8;
  const int r1 = c1 >> 2, e1 = (c1 & 3) * 8;
  const u16* a0 = A + (size_t)(m0 + r0) * K + e0;
  const u16* a1 = A + (size_t)(m0 + r1) * K + e1;
  const u16* b0 = Bt + (size_t)(n0 + r0) * K + e0;
  const u16* b1 = Bt + (size_t)(n0 + r1) * K + e1;
  u16* lA0 = &As[c0 * 8]; u16* lA1 = &As[c1 * 8];
  u16* lB0 = &Bs[c0 * 8]; u16* lB1 = &Bs[c1 * 8];

  for (int k0 = 0; k0 < K; k0 += 32) {
    __syncthreads();
    load_lds16(a0 + k0, lA0);
    load_lds16(a1 + k0, lA1);
    load_lds16(b0 + k0, lB0);
    load_lds16(b1 + k0, lB1);
    __syncthreads();
    u16x8 af[4], bfr[4];
    #pragma unroll
    for (int mi = 0; mi < 4; mi++)
      af[mi] = *(const u16x8*)&As[(wm + mi * 16 + ql) * 32 + kg * 8];
    #pragma unroll
    for (int ni = 0; ni < 4; ni++)
      bfr[ni] = *(const u16x8*)&Bs[(wn + ni * 16 + ql) * 32 + kg * 8];
    #pragma unroll
    for (int mi = 0; mi < 4; mi++)
      #pragma unroll
      for (int ni = 0; ni < 4; ni++)
        acc[mi][ni] = mfma16(af[mi], bfr[ni], acc[mi][ni]);
  }

  #pragma unroll
  for (int mi = 0; mi < 4; mi++) {
    #pragma unroll
    for (int ni = 0; ni < 4; ni++) {
      int row = m0 + wm + mi * 16 + kg * 4;
      int col = n0 + wn + ni * 16 + ql;
      #pragma unroll
      for (int r = 0; r < 4; r++) {
        if constexpr (OUT_BF16)
          Cb[(size_t)(row + r) * N + col] = f2bf(acc[mi][ni][r]);
        else
          Cf[(size_t)(row + r) * N + col] = acc[mi][ni][r];
      }
    }
  }
}

// ---------------- flash attention, causal, GQA (g=4) ----------------
// grid (16, 32 heads), 256 thr = 4 waves; block handles q-tiles {bx, 31-bx}
// (wrap-pairing: every block does exactly 33 KV-steps). KVBLK=64.
// K staged per BLOCK via global_load_lds (coalesced, double-buffered) from
// PRE-SWIZZLED global K (chunk c of row s at c^(s&7)); ds_read_b128 fragment
// reads hit all 8 bank-slots -> bandwidth floor. V staged via register commit
// into transposed padded Vt (double-buffered). ONE barrier per step; K(t+1)
// stage + V(t+1) loads issued right after it (full step to land).
// Swapped QK^T; exp2-domain softmax (Q pre-scaled by log2e/sqrt(d));
// defer-max THR=11.5.
__global__ __launch_bounds__(256, 2)
void attn_k(const u16* __restrict__ qr, const u16* __restrict__ kr,
            const u16* __restrict__ qkv, u16* __restrict__ out) {
  __shared__ alignas(16) u16 Kls[2][64 * 128];   // [buf][s][d] (chunk-swizzled)
  __shared__ alignas(16) u16 Vt[2][128][72];     // [buf][d][s+pad]
  __shared__ alignas(16) u16 Plds[4][16][72];    // per-wave [q][s+pad]
  const int tid = threadIdx.x;
  const int lane = tid & 63, wave = tid >> 6;
  const int ql = lane & 15, kg = lane >> 4;
  const int h = blockIdx.y, hk = h >> 2;

  // V staging: thread covers s in [sl4,sl4+4), d in [d0s,d0s+8); V in fused
  // qkv buffer at col 5120 + hk*128, row stride 6144.
  const int sl4 = (tid & 15) * 4;
  const int d0s = (tid >> 4) * 8;
  const u16* vbase = qkv + 5120 + (size_t)hk * 128 + d0s;
  // K staging source (global rows are pre-swizzled; pure linear row copies)
  const int krow_s = tid >> 4, kcol_s = (tid & 15) * 8;  // chunk = tid
  const u16* kbase = kr + (size_t)hk * 128 + (size_t)krow_s * 1024 + kcol_s;

  int cur = 0;
  #pragma unroll 1
  for (int half_idx = 0; half_idx < 2; half_idx++) {
    const int tile = half_idx ? (31 - (int)blockIdx.x) : (int)blockIdx.x;
    const int q0 = tile * 64;
    const int qw = q0 + wave * 16;
    const int nsteps = tile + 1;

    u16x8 qf[4];
    const u16* qbase = qr + ((size_t)(qw + ql) * 32 + h) * 128;
    #pragma unroll
    for (int kk = 0; kk < 4; kk++)
      qf[kk] = *(const u16x8*)(qbase + kk * 32 + kg * 8);

    f32x4 acc[8] = {};
    float m_run = -3e38f, l_run = 0.f;

    // protect LDS buffers from previous tile's readers, then prologue
    __syncthreads();
    cur = 0;
    // issue K stage for step 0 into Kls[0]: 4 rounds x (256 thr x 16B) = 16KB
    #pragma unroll
    for (int r = 0; r < 4; r++)
      load_lds16(kbase + (size_t)r * 16 * 1024, &Kls[0][(r * 256 + tid) * 8]);
    // V regs for step 0
    u16x8 vreg[4];
    #pragma unroll
    for (int j = 0; j < 4; j++)
      vreg[j] = *(const u16x8*)(vbase + (size_t)(sl4 + j) * 6144);

    #pragma unroll 1
    for (int t = 0; t < nsteps; t++) {
      const int s0 = t * 64;
      // (1) commit V tile t into Vt[cur] (transposed [d][s])
      #pragma unroll
      for (int e = 0; e < 8; e++) {
        ushort4 w;
        w.x = vreg[0][e]; w.y = vreg[1][e]; w.z = vreg[2][e]; w.w = vreg[3][e];
        *(ushort4*)&Vt[cur][d0s + e][sl4] = w;
      }
      __syncthreads();  // drains vmcnt: Kls[cur] staged; Vt[cur] visible
      // (2) issue K(t+1) stage into Kls[cur^1] + V(t+1) reg loads
      if (t + 1 < nsteps) {
        const u16* kn = kbase + (size_t)(s0 + 64) * 1024;
        #pragma unroll
        for (int r = 0; r < 4; r++)
          load_lds16(kn + (size_t)r * 16 * 1024, &Kls[cur ^ 1][(r * 256 + tid) * 8]);
        #pragma unroll
        for (int j = 0; j < 4; j++)
          vreg[j] = *(const u16x8*)(vbase + (size_t)(s0 + 64 + sl4 + j) * 6144);
      }
      // (3) QK^T from LDS: D[s][q], A = K rows (swizzled chunks), B = Q
      f32x4 sc[4] = {};
      __builtin_amdgcn_s_setprio(1);
      #pragma unroll
      for (int sb = 0; sb < 4; sb++) {
        const u16* krow = &Kls[cur][(sb * 16 + ql) * 128];
        #pragma unroll
        for (int kk = 0; kk < 4; kk++) {
          u16x8 kf = *(const u16x8*)(krow + (((kk * 4 + kg) ^ (ql & 7)) * 8));
          sc[sb] = mfma16(kf, qf[kk], sc[sb]);
        }
      }
      __builtin_amdgcn_s_setprio(0);
      // (4) online softmax, exp2 domain, defer-max; P overwrites sc in place
      const int qg = qw + ql;
      float mt = -3e38f;
      #pragma unroll
      for (int sb = 0; sb < 4; sb++)
        #pragma unroll
        for (int r = 0; r < 4; r++) {
          int s = s0 + sb * 16 + kg * 4 + r;
          float v = (s > qg) ? -3e38f : sc[sb][r];
          sc[sb][r] = v;
          mt = fmaxf(mt, v);
        }
      mt = fmaxf(mt, __shfl_xor(mt, 16, 64));
      mt = fmaxf(mt, __shfl_xor(mt, 32, 64));
      if (!__all(mt - m_run <= 11.5f)) {
        float m_new = fmaxf(m_run, mt);
        float fco = exp2f(m_run - m_new);
        float fr[4];
        #pragma unroll
        for (int r = 0; r < 4; r++) fr[r] = __shfl(fco, (lane & 48) | (kg * 4 + r), 64);
        #pragma unroll
        for (int db = 0; db < 8; db++)
          #pragma unroll
          for (int r = 0; r < 4; r++) acc[db][r] *= fr[r];
        l_run *= fco;
        m_run = m_new;
      }
      float rs = 0.f;
      #pragma unroll
      for (int sb = 0; sb < 4; sb++)
        #pragma unroll
        for (int r = 0; r < 4; r++) {
          float e = exp2f(sc[sb][r] - m_run);
          sc[sb][r] = e;
          rs += e;
        }
      rs += __shfl_xor(rs, 16, 64);
      rs += __shfl_xor(rs, 32, 64);
      l_run += rs;
      // (5) P -> wave-private LDS (no block barrier needed)
      #pragma unroll
      for (int sb = 0; sb < 4; sb++) {
        ushort4 pk;
        pk.x = f2bf(sc[sb][0]); pk.y = f2bf(sc[sb][1]);
        pk.z = f2bf(sc[sb][2]); pk.w = f2bf(sc[sb][3]);
        *(ushort4*)&Plds[wave][ql][sb * 16 + kg * 4] = pk;
      }
      // (6) PV: A = P[q][s], B = Vt[d][s]
      __builtin_amdgcn_s_setprio(1);
      #pragma unroll
      for (int hf = 0; hf < 2; hf++) {
        u16x8 pf = *(const u16x8*)&Plds[wave][ql][hf * 32 + kg * 8];
        #pragma unroll
        for (int db = 0; db < 8; db++) {
          u16x8 vf = *(const u16x8*)&Vt[cur][db * 16 + ql][hf * 32 + kg * 8];
          acc[db] = mfma16(pf, vf, acc[db]);
        }
      }
      __builtin_amdgcn_s_setprio(0);
      cur ^= 1;
    }

    // epilogue for this q-tile
    float linv[4];
    #pragma unroll
    for (int r = 0; r < 4; r++)
      linv[r] = 1.f / __shfl(l_run, (lane & 48) | (kg * 4 + r), 64);
    #pragma unroll
    for (int db = 0; db < 8; db++) {
      int d = db * 16 + ql;
      #pragma unroll
      for (int r = 0; r < 4; r++) {
        int q = qw + kg * 4 + r;
        out[((size_t)q * 32 + h) * 128 + d] = f2bf(acc[db][r] * linv[r]);
      }
    }
  }
}

// ---------------- launcher ----------------
extern "C" void kernel_launch(void* const* d_in, const int* in_sizes, int n_in,
                              void* d_out, int out_size, void* d_ws, size_t ws_size,
                              hipStream_t stream) {
  const float* x  = (const float*)d_in[0];
  const float* Wq = (const float*)d_in[1];
  const float* Wk = (const float*)d_in[2];
  const float* Wv = (const float*)d_in[3];
  const float* Wo = (const float*)d_in[4];
  const int* start = (const int*)d_in[5];

  const int L = 2048, HID = 4096, NH = 32, NKV = 8;
  const int NQ = 4096, NKVD = 1024, NF = 6144;

  char* ws = (char*)d_ws;
  size_t off = 0;
  auto alloc = [&](size_t bytes) {
    void* p = ws + off;
    off += (bytes + 255) & ~(size_t)255;
    return p;
  };
  u16* x_b   = (u16*)alloc((size_t)L * HID * 2);
  // Wq_t, Wk_t, Wv_t MUST be contiguous (fused GEMM reads them as one
  // 6144-row Bt). Sizes are 256B-multiples so alloc() leaves no gaps.
  u16* Wq_t  = (u16*)alloc((size_t)NQ * HID * 2);
  u16* Wk_t  = (u16*)alloc((size_t)NKVD * HID * 2);
  u16* Wv_t  = (u16*)alloc((size_t)NKVD * HID * 2);
  u16* Wo_t  = (u16*)alloc((size_t)HID * NQ * 2);
  u16* q_r   = (u16*)alloc((size_t)L * NQ * 2);
  u16* k_r   = (u16*)alloc((size_t)L * NKVD * 2);
  float2* tab = (float2*)alloc((size_t)L * 64 * sizeof(float2));
  // fused QKV output lives in d_out (25.2MB < 33.5MB); fully rewritten by the
  // final out-projection afterwards.
  u16* qkv_b  = (u16*)d_out;
  u16* attn_b = Wq_t;  // reuse Wq^T region after the fused GEMM

  const float qscale = 0.08838834764831845f * 1.4426950408889634f;  // 1/sqrt(128)*log2(e)

  // conversions / transposes / table
  cvt_f32_bf16<<<(L * HID / 4 + 255) / 256, 256, 0, stream>>>(x, x_b, L * HID / 4);
  transpose_cvt<<<dim3(HID / 32, NQ / 32), 256, 0, stream>>>(Wq, Wq_t, HID, NQ);
  transpose_cvt<<<dim3(HID / 32, NKVD / 32), 256, 0, stream>>>(Wk, Wk_t, HID, NKVD);
  transpose_cvt<<<dim3(HID / 32, NKVD / 32), 256, 0, stream>>>(Wv, Wv_t, HID, NKVD);
  transpose_cvt<<<dim3(NQ / 32, HID / 32), 256, 0, stream>>>(Wo, Wo_t, NQ, HID);
  rope_table_k<<<(L * 64 + 255) / 256, 256, 0, stream>>>(tab, start, L);

  // fused QKV projection: [2048][6144] bf16 into d_out scratch
  gemm_bt<true><<<dim3(L / 128, NF / 128), 256, 0, stream>>>(x_b, Wq_t, nullptr, qkv_b, L, NF, HID);

  // RoPE: Q (scaled, log2e folded, linear) and K (unscaled, chunk-swizzled)
  rope_apply_b<<<(L * NH * 8 + 255) / 256, 256, 0, stream>>>(qkv_b, NF, 0, q_r, tab, L * NH * 8, NH, qscale, 0);
  rope_apply_b<<<(L * NKV * 8 + 255) / 256, 256, 0, stream>>>(qkv_b, NF, NQ, k_r, tab, L * NKV * 8, NKV, 1.0f, 1);

  // attention (K via global_load_lds + swizzled ds_read; V via Vt commit)
  attn_k<<<dim3(16, NH), 256, 0, stream>>>(q_r, k_r, qkv_b, attn_b);

  // output projection (rewrites all of d_out)
  gemm_bt<false><<<dim3(L / 128, HID / 128), 256, 0, stream>>>(attn_b, Wo_t, (float*)d_out, nullptr, L, HID, NQ);
}

// Round 6
// 395.523 us; speedup vs baseline: 1.4579x; 1.0593x over previous
//
#include <hip/hip_runtime.h>

typedef unsigned short u16;
typedef float f32x4 __attribute__((ext_vector_type(4)));
typedef __bf16 bf16x8 __attribute__((ext_vector_type(8)));
typedef u16 u16x8 __attribute__((ext_vector_type(8)));

static __device__ __forceinline__ u16 f2bf(float f) {
  union { float f; unsigned u; } v; v.f = f;
  unsigned r = v.u + 0x7fffu + ((v.u >> 16) & 1u);  // RNE
  return (u16)(r >> 16);
}
static __device__ __forceinline__ float bf2f(u16 x) {
  union { unsigned u; float f; } v; v.u = (unsigned)x << 16; return v.f;
}

static __device__ __forceinline__ f32x4 mfma16(u16x8 a, u16x8 b, f32x4 c) {
  return __builtin_amdgcn_mfma_f32_16x16x32_bf16(
      __builtin_bit_cast(bf16x8, a), __builtin_bit_cast(bf16x8, b), c, 0, 0, 0);
}

static __device__ __forceinline__ void load_lds16(const void* g, void* l) {
  __builtin_amdgcn_global_load_lds(
      (const __attribute__((address_space(1))) void*)g,
      (__attribute__((address_space(3))) void*)l, 16, 0, 0);
}

// ---------------- f32 -> bf16, GEMM-A pre-swizzled (chunk c of row r at c^(r&7)) ----
// 8 elems/thread; row length 4096 (512 chunks).
__global__ void cvt_f32_bf16_swz(const float* __restrict__ in, u16* __restrict__ out, int n8) {
  int i = blockIdx.x * blockDim.x + threadIdx.x;
  if (i >= n8) return;
  int row = i >> 9;
  int j = i & 511;
  int jp = (j & ~7) | ((j & 7) ^ (row & 7));
  const float* src = in + (size_t)i * 8;
  u16x8 o;
  #pragma unroll
  for (int e = 0; e < 8; e++) o[e] = f2bf(src[e]);
  *(u16x8*)(out + ((size_t)row << 12) + jp * 8) = o;
}

// ------- transpose + convert: W[K][N] f32 -> Wt[N][K] bf16, pre-swizzled rows -------
__global__ __launch_bounds__(256)
void transpose_cvt(const float* __restrict__ W, u16* __restrict__ Wt, int K, int N) {
  __shared__ float tile[32][33];
  int tx = threadIdx.x & 31, ty = threadIdx.x >> 5;
  int k0 = blockIdx.x * 32, n0 = blockIdx.y * 32;
  #pragma unroll
  for (int i = ty; i < 32; i += 8)
    tile[i][tx] = W[(size_t)(k0 + i) * N + (n0 + tx)];
  __syncthreads();
  #pragma unroll
  for (int i = ty; i < 32; i += 8) {
    int n = n0 + i;
    int k = k0 + tx;
    Wt[(size_t)n * K + (k ^ ((n & 7) * 8))] = f2bf(tile[tx][i]);
  }
}

// ---------------- RoPE cos/sin table: [L][64] float2 ----------------
__global__ void rope_table_k(float2* __restrict__ tab, const int* __restrict__ start, int L) {
  int i = blockIdx.x * blockDim.x + threadIdx.x;
  if (i >= L * 64) return;
  int p = i >> 6, j = i & 63;
  float inv = powf(10000.0f, -(float)j / 64.0f);
  float ang = (float)(p + start[0]) * inv;
  tab[i] = make_float2(cosf(ang), sinf(ang));
}

// ---------------- RoPE apply (bf16 in, strided) -> bf16 [L][H][128], * scale ----------
// swz!=0: store 16B-chunk c of row p at chunk c^(p&7) within each 64-elem half
// (pre-swizzle for conflict-free LDS reads after linear global_load_lds staging).
__global__ void rope_apply_b(const u16* __restrict__ in, int istride, int icol,
                             u16* __restrict__ outp, const float2* __restrict__ tab,
                             int total, int H, float scale, int swz) {
  int i = blockIdx.x * blockDim.x + threadIdx.x;  // total = L*H*8
  if (i >= total) return;
  int j8 = (i & 7) * 8;
  int h = (i >> 3) % H;
  int p = i / (8 * H);
  const u16* base = in + (size_t)p * istride + icol + h * 128;
  u16x8 a = *(const u16x8*)(base + j8);
  u16x8 b = *(const u16x8*)(base + j8 + 64);
  u16x8 o1, o2;
  #pragma unroll
  for (int e = 0; e < 8; e++) {
    float2 cs = tab[p * 64 + j8 + e];
    float av = bf2f(a[e]), bv = bf2f(b[e]);
    o1[e] = f2bf((av * cs.x - bv * cs.y) * scale);
    o2[e] = f2bf((av * cs.y + bv * cs.x) * scale);
  }
  int c1 = i & 7;
  int cs1 = swz ? (c1 ^ (p & 7)) : c1;
  u16* ob = outp + ((size_t)p * H + h) * 128 + cs1 * 8;
  *(u16x8*)ob = o1;
  *(u16x8*)(ob + 64) = o2;   // chunk c1+8 -> swizzled (c1+8)^(p&7) = cs1+8
}

// ---------------- GEMM: C = A[M][K] @ Bt[N][K], 256-wide tiles, counted vmcnt -------
// BM=256, BK=64, 512 thr (8 waves, WM x WN). A and Bt are PRE-SWIZZLED in global
// (chunk c of row r at c^(r&7) within aligned 64-col groups) -> staging is a linear
// global_load_lds row copy; frag ds_read_b128 applies the XOR (2 lanes/bank = free).
// Double-buffered LDS; stage K-tile t+2 while computing t; vmcnt(LOADS) waits only
// t+1's loads (t+2's stay in flight) -> no vmcnt(0) drain in the main loop.
// Safety: barrier #1 is crossed only after every wave's 24 frag reads were consumed
// by MFMA (compiler lgkm waits), so stage writes to buf[t&1] cannot race reads.
template<int BN, int WM, int WN, bool OUT_BF16>
__global__ __launch_bounds__(512, 2)
void gemm256(const u16* __restrict__ A, const u16* __restrict__ Bt,
             float* __restrict__ Cf, u16* __restrict__ Cb, int N, int K, int gm) {
  constexpr int BM = 256;
  constexpr int M_REP = BM / WM / 16;
  constexpr int N_REP = BN / WN / 16;
  constexpr int LOADS_A = 4;        // 256*8 chunks / 512 thr
  constexpr int LOADS_B = BN / 64;  // BN*8 chunks / 512 thr
  __shared__ alignas(16) u16 As[2][BM * 64];
  __shared__ alignas(16) u16 Bs[2][BN * 64];
  const int tid = threadIdx.x;
  const int lane = tid & 63;
  const int wid = tid >> 6;
  const int ql = lane & 15, kg = lane >> 4;
  const int wr = wid / WN, wcn = wid % WN;

  // XCD-aware bijective block swizzle (grid % 8 == 0 for all our launches)
  const int nb = gridDim.x;
  const int b = blockIdx.x;
  const int swz = (b & 7) * (nb >> 3) + (b >> 3);
  const int m0 = (swz % gm) * BM;
  const int n0 = (swz / gm) * BN;

  // staging source (linear copy of pre-swizzled rows); thread -> (row tid>>3, chunk tid&7)
  const int srow = tid >> 3;
  const u16* asrc = A + (size_t)(m0 + srow) * K + (tid & 7) * 8;
  const u16* bsrc = Bt + (size_t)(n0 + srow) * K + (tid & 7) * 8;

  auto stage = [&](int t, int buf) {
    const u16* ap = asrc + t * 64;
    #pragma unroll
    for (int r = 0; r < LOADS_A; r++)
      load_lds16(ap + (size_t)(r * 64) * K, &As[buf][(r * 512 + tid) * 8]);
    const u16* bp = bsrc + t * 64;
    #pragma unroll
    for (int r = 0; r < LOADS_B; r++)
      load_lds16(bp + (size_t)(r * 64) * K, &Bs[buf][(r * 512 + tid) * 8]);
  };

  f32x4 acc[M_REP][N_REP] = {};
  const int NT = K / 64;

  stage(0, 0);
  stage(1, 1);
  if constexpr (LOADS_A + LOADS_B == 8)
    asm volatile("s_waitcnt vmcnt(8)" ::: "memory");
  else
    asm volatile("s_waitcnt vmcnt(6)" ::: "memory");
  __builtin_amdgcn_sched_barrier(0);
  __builtin_amdgcn_s_barrier();

  #pragma unroll 1
  for (int t = 0; t < NT; t++) {
    const int cur = t & 1;
    #pragma unroll
    for (int kk = 0; kk < 2; kk++) {
      u16x8 af[M_REP], bfr[N_REP];
      #pragma unroll
      for (int mi = 0; mi < M_REP; mi++) {
        int r = wr * (M_REP * 16) + mi * 16 + ql;
        af[mi] = *(const u16x8*)&As[cur][(r * 8 + (((kk << 2) | kg) ^ (ql & 7))) * 8];
      }
      #pragma unroll
      for (int ni = 0; ni < N_REP; ni++) {
        int r = wcn * (N_REP * 16) + ni * 16 + ql;
        bfr[ni] = *(const u16x8*)&Bs[cur][(r * 8 + (((kk << 2) | kg) ^ (ql & 7))) * 8];
      }
      __builtin_amdgcn_s_setprio(1);
      #pragma unroll
      for (int mi = 0; mi < M_REP; mi++)
        #pragma unroll
        for (int ni = 0; ni < N_REP; ni++)
          acc[mi][ni] = mfma16(af[mi], bfr[ni], acc[mi][ni]);
      __builtin_amdgcn_s_setprio(0);
    }
    // all of this wave's reads of buf[cur] are consumed (lgkm-waited before MFMA)
    __builtin_amdgcn_sched_barrier(0);
    __builtin_amdgcn_s_barrier();           // every wave done with buf[cur]
    if (t + 2 < NT) {
      stage(t + 2, cur);                    // overwrite buf[cur]; t+1 untouched
      if constexpr (LOADS_A + LOADS_B == 8)
        asm volatile("s_waitcnt vmcnt(8)" ::: "memory");   // t+1 landed, t+2 in flight
      else
        asm volatile("s_waitcnt vmcnt(6)" ::: "memory");
    } else {
      asm volatile("s_waitcnt vmcnt(0)" ::: "memory");     // tail drain
    }
    __builtin_amdgcn_sched_barrier(0);
    __builtin_amdgcn_s_barrier();           // buf[cur^1] (t+1) visible to all
  }

  #pragma unroll
  for (int mi = 0; mi < M_REP; mi++) {
    #pragma unroll
    for (int ni = 0; ni < N_REP; ni++) {
      int row0 = m0 + wr * (M_REP * 16) + mi * 16 + kg * 4;
      int col = n0 + wcn * (N_REP * 16) + ni * 16 + ql;
      #pragma unroll
      for (int r = 0; r < 4; r++) {
        if constexpr (OUT_BF16)
          Cb[(size_t)(row0 + r) * N + col] = f2bf(acc[mi][ni][r]);
        else
          Cf[(size_t)(row0 + r) * N + col] = acc[mi][ni][r];
      }
    }
  }
}

// ---------------- flash attention, causal, GQA (g=4) ----------------
// grid (16, 32 heads), 256 thr = 4 waves; block handles q-tiles {bx, 31-bx}
// (wrap-pairing: every block does exactly 33 KV-steps). KVBLK=64.
// K staged per BLOCK via global_load_lds (coalesced, double-buffered) from
// PRE-SWIZZLED global K; V staged via register commit into transposed padded Vt.
// ONE barrier per step. Swapped QK^T; exp2-domain softmax; defer-max THR=11.5.
// Epilogue writes the out-proj A-matrix PRE-SWIZZLED (chunk XOR on column).
__global__ __launch_bounds__(256, 2)
void attn_k(const u16* __restrict__ qr, const u16* __restrict__ kr,
            const u16* __restrict__ qkv, u16* __restrict__ out) {
  __shared__ alignas(16) u16 Kls[2][64 * 128];   // [buf][s][d] (chunk-swizzled)
  __shared__ alignas(16) u16 Vt[2][128][72];     // [buf][d][s+pad]
  __shared__ alignas(16) u16 Plds[4][16][72];    // per-wave [q][s+pad]
  const int tid = threadIdx.x;
  const int lane = tid & 63, wave = tid >> 6;
  const int ql = lane & 15, kg = lane >> 4;
  const int h = blockIdx.y, hk = h >> 2;

  const int sl4 = (tid & 15) * 4;
  const int d0s = (tid >> 4) * 8;
  const u16* vbase = qkv + 5120 + (size_t)hk * 128 + d0s;
  const int krow_s = tid >> 4, kcol_s = (tid & 15) * 8;
  const u16* kbase = kr + (size_t)hk * 128 + (size_t)krow_s * 1024 + kcol_s;

  int cur = 0;
  #pragma unroll 1
  for (int half_idx = 0; half_idx < 2; half_idx++) {
    const int tile = half_idx ? (31 - (int)blockIdx.x) : (int)blockIdx.x;
    const int q0 = tile * 64;
    const int qw = q0 + wave * 16;
    const int nsteps = tile + 1;

    u16x8 qf[4];
    const u16* qbase = qr + ((size_t)(qw + ql) * 32 + h) * 128;
    #pragma unroll
    for (int kk = 0; kk < 4; kk++)
      qf[kk] = *(const u16x8*)(qbase + kk * 32 + kg * 8);

    f32x4 acc[8] = {};
    float m_run = -3e38f, l_run = 0.f;

    __syncthreads();
    cur = 0;
    #pragma unroll
    for (int r = 0; r < 4; r++)
      load_lds16(kbase + (size_t)r * 16 * 1024, &Kls[0][(r * 256 + tid) * 8]);
    u16x8 vreg[4];
    #pragma unroll
    for (int j = 0; j < 4; j++)
      vreg[j] = *(const u16x8*)(vbase + (size_t)(sl4 + j) * 6144);

    #pragma unroll 1
    for (int t = 0; t < nsteps; t++) {
      const int s0 = t * 64;
      #pragma unroll
      for (int e = 0; e < 8; e++) {
        ushort4 w;
        w.x = vreg[0][e]; w.y = vreg[1][e]; w.z = vreg[2][e]; w.w = vreg[3][e];
        *(ushort4*)&Vt[cur][d0s + e][sl4] = w;
      }
      __syncthreads();  // the ONLY barrier per step
      if (t + 1 < nsteps) {
        const u16* kn = kbase + (size_t)(s0 + 64) * 1024;
        #pragma unroll
        for (int r = 0; r < 4; r++)
          load_lds16(kn + (size_t)r * 16 * 1024, &Kls[cur ^ 1][(r * 256 + tid) * 8]);
        #pragma unroll
        for (int j = 0; j < 4; j++)
          vreg[j] = *(const u16x8*)(vbase + (size_t)(s0 + 64 + sl4 + j) * 6144);
      }
      f32x4 sc[4] = {};
      __builtin_amdgcn_s_setprio(1);
      #pragma unroll
      for (int sb = 0; sb < 4; sb++) {
        const u16* krow = &Kls[cur][(sb * 16 + ql) * 128];
        #pragma unroll
        for (int kk = 0; kk < 4; kk++) {
          u16x8 kf = *(const u16x8*)(krow + (((kk * 4 + kg) ^ (ql & 7)) * 8));
          sc[sb] = mfma16(kf, qf[kk], sc[sb]);
        }
      }
      __builtin_amdgcn_s_setprio(0);
      const int qg = qw + ql;
      float mt = -3e38f;
      #pragma unroll
      for (int sb = 0; sb < 4; sb++)
        #pragma unroll
        for (int r = 0; r < 4; r++) {
          int s = s0 + sb * 16 + kg * 4 + r;
          float v = (s > qg) ? -3e38f : sc[sb][r];
          sc[sb][r] = v;
          mt = fmaxf(mt, v);
        }
      mt = fmaxf(mt, __shfl_xor(mt, 16, 64));
      mt = fmaxf(mt, __shfl_xor(mt, 32, 64));
      if (!__all(mt - m_run <= 11.5f)) {
        float m_new = fmaxf(m_run, mt);
        float fco = exp2f(m_run - m_new);
        float fr[4];
        #pragma unroll
        for (int r = 0; r < 4; r++) fr[r] = __shfl(fco, (lane & 48) | (kg * 4 + r), 64);
        #pragma unroll
        for (int db = 0; db < 8; db++)
          #pragma unroll
          for (int r = 0; r < 4; r++) acc[db][r] *= fr[r];
        l_run *= fco;
        m_run = m_new;
      }
      float rs = 0.f;
      #pragma unroll
      for (int sb = 0; sb < 4; sb++)
        #pragma unroll
        for (int r = 0; r < 4; r++) {
          float e = exp2f(sc[sb][r] - m_run);
          sc[sb][r] = e;
          rs += e;
        }
      rs += __shfl_xor(rs, 16, 64);
      rs += __shfl_xor(rs, 32, 64);
      l_run += rs;
      #pragma unroll
      for (int sb = 0; sb < 4; sb++) {
        ushort4 pk;
        pk.x = f2bf(sc[sb][0]); pk.y = f2bf(sc[sb][1]);
        pk.z = f2bf(sc[sb][2]); pk.w = f2bf(sc[sb][3]);
        *(ushort4*)&Plds[wave][ql][sb * 16 + kg * 4] = pk;
      }
      __builtin_amdgcn_s_setprio(1);
      #pragma unroll
      for (int hf = 0; hf < 2; hf++) {
        u16x8 pf = *(const u16x8*)&Plds[wave][ql][hf * 32 + kg * 8];
        #pragma unroll
        for (int db = 0; db < 8; db++) {
          u16x8 vf = *(const u16x8*)&Vt[cur][db * 16 + ql][hf * 32 + kg * 8];
          acc[db] = mfma16(pf, vf, acc[db]);
        }
      }
      __builtin_amdgcn_s_setprio(0);
      cur ^= 1;
    }

    // epilogue: write PRE-SWIZZLED for the out-projection's A staging
    float linv[4];
    #pragma unroll
    for (int r = 0; r < 4; r++)
      linv[r] = 1.f / __shfl(l_run, (lane & 48) | (kg * 4 + r), 64);
    #pragma unroll
    for (int db = 0; db < 8; db++) {
      int d = db * 16 + ql;
      #pragma unroll
      for (int r = 0; r < 4; r++) {
        int q = qw + kg * 4 + r;
        int col = (h * 128 + d) ^ ((q & 7) << 3);
        out[(size_t)q * 4096 + col] = f2bf(acc[db][r] * linv[r]);
      }
    }
  }
}

// ---------------- launcher ----------------
extern "C" void kernel_launch(void* const* d_in, const int* in_sizes, int n_in,
                              void* d_out, int out_size, void* d_ws, size_t ws_size,
                              hipStream_t stream) {
  const float* x  = (const float*)d_in[0];
  const float* Wq = (const float*)d_in[1];
  const float* Wk = (const float*)d_in[2];
  const float* Wv = (const float*)d_in[3];
  const float* Wo = (const float*)d_in[4];
  const int* start = (const int*)d_in[5];

  const int L = 2048, HID = 4096, NH = 32, NKV = 8;
  const int NQ = 4096, NKVD = 1024, NF = 6144;

  char* ws = (char*)d_ws;
  size_t off = 0;
  auto alloc = [&](size_t bytes) {
    void* p = ws + off;
    off += (bytes + 255) & ~(size_t)255;
    return p;
  };
  u16* x_b   = (u16*)alloc((size_t)L * HID * 2);
  // Wq_t, Wk_t, Wv_t MUST be contiguous (fused GEMM reads them as one
  // 6144-row Bt). Sizes are 256B-multiples so alloc() leaves no gaps.
  u16* Wq_t  = (u16*)alloc((size_t)NQ * HID * 2);
  u16* Wk_t  = (u16*)alloc((size_t)NKVD * HID * 2);
  u16* Wv_t  = (u16*)alloc((size_t)NKVD * HID * 2);
  u16* Wo_t  = (u16*)alloc((size_t)HID * NQ * 2);
  u16* q_r   = (u16*)alloc((size_t)L * NQ * 2);
  u16* k_r   = (u16*)alloc((size_t)L * NKVD * 2);
  float2* tab = (float2*)alloc((size_t)L * 64 * sizeof(float2));
  u16* qkv_b  = (u16*)d_out;   // fused QKV output; fully rewritten by out-proj
  u16* attn_b = Wq_t;          // reuse Wq^T region after the fused GEMM

  const float qscale = 0.08838834764831845f * 1.4426950408889634f;  // 1/sqrt(128)*log2(e)

  // conversions / transposes / table (all GEMM inputs pre-swizzled)
  cvt_f32_bf16_swz<<<(L * HID / 8 + 255) / 256, 256, 0, stream>>>(x, x_b, L * HID / 8);
  transpose_cvt<<<dim3(HID / 32, NQ / 32), 256, 0, stream>>>(Wq, Wq_t, HID, NQ);
  transpose_cvt<<<dim3(HID / 32, NKVD / 32), 256, 0, stream>>>(Wk, Wk_t, HID, NKVD);
  transpose_cvt<<<dim3(HID / 32, NKVD / 32), 256, 0, stream>>>(Wv, Wv_t, HID, NKVD);
  transpose_cvt<<<dim3(NQ / 32, HID / 32), 256, 0, stream>>>(Wo, Wo_t, NQ, HID);
  rope_table_k<<<(L * 64 + 255) / 256, 256, 0, stream>>>(tab, start, L);

  // fused QKV projection: [2048][6144] bf16 (256x256 tiles, grid 8x24=192)
  gemm256<256, 2, 4, true><<<192, 512, 0, stream>>>(x_b, Wq_t, nullptr, qkv_b, NF, HID, 8);

  // RoPE: Q (scaled, log2e folded, linear) and K (unscaled, chunk-swizzled)
  rope_apply_b<<<(L * NH * 8 + 255) / 256, 256, 0, stream>>>(qkv_b, NF, 0, q_r, tab, L * NH * 8, NH, qscale, 0);
  rope_apply_b<<<(L * NKV * 8 + 255) / 256, 256, 0, stream>>>(qkv_b, NF, NQ, k_r, tab, L * NKV * 8, NKV, 1.0f, 1);

  // attention (K via global_load_lds + swizzled ds_read; V via Vt commit)
  attn_k<<<dim3(16, NH), 256, 0, stream>>>(q_r, k_r, qkv_b, attn_b);

  // output projection: 256x128 tiles, grid 8x32=256 (1 block/CU exactly)
  gemm256<128, 4, 2, false><<<256, 512, 0, stream>>>(attn_b, Wo_t, (float*)d_out, nullptr, HID, NQ, 8);
}

// Round 7
// 376.223 us; speedup vs baseline: 1.5327x; 1.0513x over previous
//
#include <hip/hip_runtime.h>

typedef unsigned short u16;
typedef float f32x4 __attribute__((ext_vector_type(4)));
typedef __bf16 bf16x8 __attribute__((ext_vector_type(8)));
typedef u16 u16x8 __attribute__((ext_vector_type(8)));

static __device__ __forceinline__ u16 f2bf(float f) {
  union { float f; unsigned u; } v; v.f = f;
  unsigned r = v.u + 0x7fffu + ((v.u >> 16) & 1u);  // RNE
  return (u16)(r >> 16);
}
static __device__ __forceinline__ float bf2f(u16 x) {
  union { unsigned u; float f; } v; v.u = (unsigned)x << 16; return v.f;
}

static __device__ __forceinline__ f32x4 mfma16(u16x8 a, u16x8 b, f32x4 c) {
  return __builtin_amdgcn_mfma_f32_16x16x32_bf16(
      __builtin_bit_cast(bf16x8, a), __builtin_bit_cast(bf16x8, b), c, 0, 0, 0);
}

static __device__ __forceinline__ void load_lds16(const void* g, void* l) {
  __builtin_amdgcn_global_load_lds(
      (const __attribute__((address_space(1))) void*)g,
      (__attribute__((address_space(3))) void*)l, 16, 0, 0);
}

// ---------------- f32 -> bf16, GEMM-A pre-swizzled (chunk c of row r at c^(r&7)) ----
__global__ void cvt_f32_bf16_swz(const float* __restrict__ in, u16* __restrict__ out, int n8) {
  int i = blockIdx.x * blockDim.x + threadIdx.x;
  if (i >= n8) return;
  int row = i >> 9;
  int j = i & 511;
  int jp = (j & ~7) | ((j & 7) ^ (row & 7));
  const float* src = in + (size_t)i * 8;
  u16x8 o;
  #pragma unroll
  for (int e = 0; e < 8; e++) o[e] = f2bf(src[e]);
  *(u16x8*)(out + ((size_t)row << 12) + jp * 8) = o;
}

// ------- transpose + convert: W[K][N] f32 -> Wt[N][K] bf16, pre-swizzled rows -------
__global__ __launch_bounds__(256)
void transpose_cvt(const float* __restrict__ W, u16* __restrict__ Wt, int K, int N) {
  __shared__ float tile[32][33];
  int tx = threadIdx.x & 31, ty = threadIdx.x >> 5;
  int k0 = blockIdx.x * 32, n0 = blockIdx.y * 32;
  #pragma unroll
  for (int i = ty; i < 32; i += 8)
    tile[i][tx] = W[(size_t)(k0 + i) * N + (n0 + tx)];
  __syncthreads();
  #pragma unroll
  for (int i = ty; i < 32; i += 8) {
    int n = n0 + i;
    int k = k0 + tx;
    Wt[(size_t)n * K + (k ^ ((n & 7) * 8))] = f2bf(tile[tx][i]);
  }
}

// ---------------- RoPE cos/sin table: [L][64] float2 ----------------
__global__ void rope_table_k(float2* __restrict__ tab, const int* __restrict__ start, int L) {
  int i = blockIdx.x * blockDim.x + threadIdx.x;
  if (i >= L * 64) return;
  int p = i >> 6, j = i & 63;
  float inv = powf(10000.0f, -(float)j / 64.0f);
  float ang = (float)(p + start[0]) * inv;
  tab[i] = make_float2(cosf(ang), sinf(ang));
}

// ---------------- RoPE apply (bf16 in, strided) -> bf16 [L][H][128], * scale ----------
__global__ void rope_apply_b(const u16* __restrict__ in, int istride, int icol,
                             u16* __restrict__ outp, const float2* __restrict__ tab,
                             int total, int H, float scale, int swz) {
  int i = blockIdx.x * blockDim.x + threadIdx.x;  // total = L*H*8
  if (i >= total) return;
  int j8 = (i & 7) * 8;
  int h = (i >> 3) % H;
  int p = i / (8 * H);
  const u16* base = in + (size_t)p * istride + icol + h * 128;
  u16x8 a = *(const u16x8*)(base + j8);
  u16x8 b = *(const u16x8*)(base + j8 + 64);
  u16x8 o1, o2;
  #pragma unroll
  for (int e = 0; e < 8; e++) {
    float2 cs = tab[p * 64 + j8 + e];
    float av = bf2f(a[e]), bv = bf2f(b[e]);
    o1[e] = f2bf((av * cs.x - bv * cs.y) * scale);
    o2[e] = f2bf((av * cs.y + bv * cs.x) * scale);
  }
  int c1 = i & 7;
  int cs1 = swz ? (c1 ^ (p & 7)) : c1;
  u16* ob = outp + ((size_t)p * H + h) * 128 + cs1 * 8;
  *(u16x8*)ob = o1;
  *(u16x8*)(ob + 64) = o2;
}

// ======== 8-phase GEMM: C = A[M][K] @ Bt[N][K]; BM=256, BK=64, 512 thr (2x4 waves) ==
// 8 phases/iter, 2 K-tiles/iter. Quadrant (m-half, n2-half) per phase; A-frags reused
// across n2, both B n2-sets held in regs -> 24 ds_reads/K-tile. Stage schedule per
// tile (4 phases, starting 4 phases before its first read): [Aq0,Aq2][B(n2=0)]
// [B(n2=1)][Aq1,Aq3] -> stage-to-read distance 3-4 phases, guaranteed by per-phase
// counted vmcnt (in-order retirement); never drains in the main loop. WAR: each
// staged region's last LDS-read is >=3 barriers earlier (per-region verified).
// B LDS is stripe-interleaved [n2][j][STR][64] so stage rounds align with quadrant
// reads; LDS-row&7 == global-row&7 everywhere, so the global chunk pre-swizzle
// (c^(row&7)) is read back with the same XOR -> conflict-free ds_read_b128.
template<int BN, bool OUT_BF16>
__global__ __launch_bounds__(512, 2)
void gemm8p(const u16* __restrict__ A, const u16* __restrict__ Bt,
            float* __restrict__ Cf, u16* __restrict__ Cb, int N, int K, int gm) {
  constexpr int N_REP = BN / 64;        // 4 (BN=256) or 2 (BN=128)
  constexpr int NHALF = N_REP / 2;      // 2 or 1
  constexpr int STR = 16 * NHALF;       // 32 or 16
  constexpr int BJP = (BN == 256) ? 2 : 1;  // B stage rounds per n2
  __shared__ alignas(16) u16 As[2][256 * 64];
  __shared__ alignas(16) u16 Bs[2][BN * 64];
  const int tid = threadIdx.x;
  const int lane = tid & 63;
  const int wid = tid >> 6;
  const int ql = lane & 15, kg = lane >> 4;
  const int wr = wid >> 2, wcn = wid & 3;

  // XCD-aware bijective block swizzle (grid % 8 == 0)
  const int nb = gridDim.x;
  const int b = blockIdx.x;
  const int swz = (b & 7) * (nb >> 3) + (b >> 3);
  const int m0 = (swz % gm) * 256;
  const int n0 = (swz / gm) * BN;

  const int srow = tid >> 3, schk = tid & 7;
  const u16* abase = A + (size_t)(m0 + srow) * K + schk * 8;
  const u16* bbase = Bt + (size_t)n0 * K + schk * 8;

  auto stageA = [&](int buf, int t, int qa) {
    load_lds16(abase + (size_t)(qa * 64) * K + t * 64,
               &As[buf][((qa * 64 + srow) * 8 + schk) * 8]);
  };
  auto stageB = [&](int buf, int t, int n2, int jp) {
    int j = jp * (64 / STR) + srow / STR;
    int r = srow % STR;
    int g = j * (2 * STR) + n2 * STR + r;
    load_lds16(bbase + (size_t)g * K + t * 64,
               &Bs[buf][((n2 * (BN / 2) + jp * 64 + srow) * 8 + schk) * 8]);
  };

  f32x4 acc[8][N_REP] = {};
  u16x8 af[4][2];
  u16x8 bfr[2][NHALF][2];
  const int NT = K / 64;

  // prologue: tile 0 -> buf0 fully, one-time drain
  stageA(0, 0, 0); stageA(0, 0, 2);
  #pragma unroll
  for (int jp = 0; jp < BJP; jp++) stageB(0, 0, 0, jp);
  #pragma unroll
  for (int jp = 0; jp < BJP; jp++) stageB(0, 0, 1, jp);
  stageA(0, 0, 1); stageA(0, 0, 3);
  asm volatile("s_waitcnt vmcnt(0)" ::: "memory");
  __builtin_amdgcn_sched_barrier(0);
  __builtin_amdgcn_s_barrier();

  #pragma unroll 1
  for (int i = 0; i < NT / 2; i++) {
    #pragma unroll
    for (int p = 0; p < 8; p++) {
      const int q = p & 3;
      const int m = q >> 1, n2 = q & 1;
      const int cbuf = (p < 4) ? 0 : 1;   // compute tile 2i (buf0) then 2i+1 (buf1)
      // counted vmem gate: stages >=3 phases old are in LDS (in-order retirement)
      if constexpr (BN == 256)
        asm volatile("s_waitcnt vmcnt(4)" ::: "memory");
      else
        asm volatile("s_waitcnt vmcnt(2)" ::: "memory");
      __builtin_amdgcn_sched_barrier(0);
      // ds_reads for this quadrant (A at q0/q2; B at q0/q1; q3 reuses regs)
      if (q == 0 || q == 2) {
        #pragma unroll
        for (int mi = 0; mi < 4; mi++)
          #pragma unroll
          for (int kk = 0; kk < 2; kk++) {
            int row = wr * 128 + m * 64 + mi * 16 + ql;
            int ch = ((kk << 2) | kg) ^ (ql & 7);
            af[mi][kk] = *(const u16x8*)&As[cbuf][(row * 8 + ch) * 8];
          }
      }
      if (q == 0 || q == 1) {
        #pragma unroll
        for (int ni = 0; ni < NHALF; ni++)
          #pragma unroll
          for (int kk = 0; kk < 2; kk++) {
            int R = q * (BN / 2) + wcn * STR + ni * 16 + ql;  // q == n2 here
            int ch = ((kk << 2) | kg) ^ (ql & 7);
            bfr[q][ni][kk] = *(const u16x8*)&Bs[cbuf][(R * 8 + ch) * 8];
          }
      }
      // stage rounds (phases 0-3: tile 2i+1 -> buf1; 4-7: tile 2i+2 -> buf0)
      const int st = 2 * i + 1 + (p >= 4 ? 1 : 0);
      const int sbuf = st & 1;
      if (st < NT) {
        if (q == 0) { stageA(sbuf, st, 0); stageA(sbuf, st, 2); }
        else if (q == 1) {
          #pragma unroll
          for (int jp = 0; jp < BJP; jp++) stageB(sbuf, st, 0, jp);
        } else if (q == 2) {
          #pragma unroll
          for (int jp = 0; jp < BJP; jp++) stageB(sbuf, st, 1, jp);
        } else { stageA(sbuf, st, 1); stageA(sbuf, st, 3); }
      }
      __builtin_amdgcn_sched_barrier(0);
      __builtin_amdgcn_s_barrier();
      __builtin_amdgcn_sched_barrier(0);
      __builtin_amdgcn_s_setprio(1);
      #pragma unroll
      for (int mi = 0; mi < 4; mi++)
        #pragma unroll
        for (int ni = 0; ni < NHALF; ni++)
          #pragma unroll
          for (int kk = 0; kk < 2; kk++)
            acc[m * 4 + mi][n2 * NHALF + ni] =
                mfma16(af[mi][kk], bfr[n2][ni][kk], acc[m * 4 + mi][n2 * NHALF + ni]);
      __builtin_amdgcn_s_setprio(0);
      __builtin_amdgcn_sched_barrier(0);
      __builtin_amdgcn_s_barrier();
    }
  }
  asm volatile("s_waitcnt vmcnt(0)" ::: "memory");

  #pragma unroll
  for (int mi = 0; mi < 8; mi++) {
    #pragma unroll
    for (int ni = 0; ni < N_REP; ni++) {
      int row0 = m0 + wr * 128 + mi * 16 + kg * 4;
      int col = n0 + wcn * (16 * N_REP) + ni * 16 + ql;
      #pragma unroll
      for (int r = 0; r < 4; r++) {
        if constexpr (OUT_BF16)
          Cb[(size_t)(row0 + r) * N + col] = f2bf(acc[mi][ni][r]);
        else
          Cf[(size_t)(row0 + r) * N + col] = acc[mi][ni][r];
      }
    }
  }
}

// ---------------- flash attention, causal, GQA (g=4) ----------------
// (unchanged from R6: K via pre-swizzled global_load_lds + swizzled ds_read;
//  V via register-commit transposed Vt; one barrier/step; exp2 softmax;
//  epilogue writes out-proj A pre-swizzled)
__global__ __launch_bounds__(256, 2)
void attn_k(const u16* __restrict__ qr, const u16* __restrict__ kr,
            const u16* __restrict__ qkv, u16* __restrict__ out) {
  __shared__ alignas(16) u16 Kls[2][64 * 128];
  __shared__ alignas(16) u16 Vt[2][128][72];
  __shared__ alignas(16) u16 Plds[4][16][72];
  const int tid = threadIdx.x;
  const int lane = tid & 63, wave = tid >> 6;
  const int ql = lane & 15, kg = lane >> 4;
  const int h = blockIdx.y, hk = h >> 2;

  const int sl4 = (tid & 15) * 4;
  const int d0s = (tid >> 4) * 8;
  const u16* vbase = qkv + 5120 + (size_t)hk * 128 + d0s;
  const int krow_s = tid >> 4, kcol_s = (tid & 15) * 8;
  const u16* kbase = kr + (size_t)hk * 128 + (size_t)krow_s * 1024 + kcol_s;

  int cur = 0;
  #pragma unroll 1
  for (int half_idx = 0; half_idx < 2; half_idx++) {
    const int tile = half_idx ? (31 - (int)blockIdx.x) : (int)blockIdx.x;
    const int q0 = tile * 64;
    const int qw = q0 + wave * 16;
    const int nsteps = tile + 1;

    u16x8 qf[4];
    const u16* qbase = qr + ((size_t)(qw + ql) * 32 + h) * 128;
    #pragma unroll
    for (int kk = 0; kk < 4; kk++)
      qf[kk] = *(const u16x8*)(qbase + kk * 32 + kg * 8);

    f32x4 acc[8] = {};
    float m_run = -3e38f, l_run = 0.f;

    __syncthreads();
    cur = 0;
    #pragma unroll
    for (int r = 0; r < 4; r++)
      load_lds16(kbase + (size_t)r * 16 * 1024, &Kls[0][(r * 256 + tid) * 8]);
    u16x8 vreg[4];
    #pragma unroll
    for (int j = 0; j < 4; j++)
      vreg[j] = *(const u16x8*)(vbase + (size_t)(sl4 + j) * 6144);

    #pragma unroll 1
    for (int t = 0; t < nsteps; t++) {
      const int s0 = t * 64;
      #pragma unroll
      for (int e = 0; e < 8; e++) {
        ushort4 w;
        w.x = vreg[0][e]; w.y = vreg[1][e]; w.z = vreg[2][e]; w.w = vreg[3][e];
        *(ushort4*)&Vt[cur][d0s + e][sl4] = w;
      }
      __syncthreads();  // the ONLY barrier per step
      if (t + 1 < nsteps) {
        const u16* kn = kbase + (size_t)(s0 + 64) * 1024;
        #pragma unroll
        for (int r = 0; r < 4; r++)
          load_lds16(kn + (size_t)r * 16 * 1024, &Kls[cur ^ 1][(r * 256 + tid) * 8]);
        #pragma unroll
        for (int j = 0; j < 4; j++)
          vreg[j] = *(const u16x8*)(vbase + (size_t)(s0 + 64 + sl4 + j) * 6144);
      }
      f32x4 sc[4] = {};
      __builtin_amdgcn_s_setprio(1);
      #pragma unroll
      for (int sb = 0; sb < 4; sb++) {
        const u16* krow = &Kls[cur][(sb * 16 + ql) * 128];
        #pragma unroll
        for (int kk = 0; kk < 4; kk++) {
          u16x8 kf = *(const u16x8*)(krow + (((kk * 4 + kg) ^ (ql & 7)) * 8));
          sc[sb] = mfma16(kf, qf[kk], sc[sb]);
        }
      }
      __builtin_amdgcn_s_setprio(0);
      const int qg = qw + ql;
      float mt = -3e38f;
      #pragma unroll
      for (int sb = 0; sb < 4; sb++)
        #pragma unroll
        for (int r = 0; r < 4; r++) {
          int s = s0 + sb * 16 + kg * 4 + r;
          float v = (s > qg) ? -3e38f : sc[sb][r];
          sc[sb][r] = v;
          mt = fmaxf(mt, v);
        }
      mt = fmaxf(mt, __shfl_xor(mt, 16, 64));
      mt = fmaxf(mt, __shfl_xor(mt, 32, 64));
      if (!__all(mt - m_run <= 11.5f)) {
        float m_new = fmaxf(m_run, mt);
        float fco = exp2f(m_run - m_new);
        float fr[4];
        #pragma unroll
        for (int r = 0; r < 4; r++) fr[r] = __shfl(fco, (lane & 48) | (kg * 4 + r), 64);
        #pragma unroll
        for (int db = 0; db < 8; db++)
          #pragma unroll
          for (int r = 0; r < 4; r++) acc[db][r] *= fr[r];
        l_run *= fco;
        m_run = m_new;
      }
      float rs = 0.f;
      #pragma unroll
      for (int sb = 0; sb < 4; sb++)
        #pragma unroll
        for (int r = 0; r < 4; r++) {
          float e = exp2f(sc[sb][r] - m_run);
          sc[sb][r] = e;
          rs += e;
        }
      rs += __shfl_xor(rs, 16, 64);
      rs += __shfl_xor(rs, 32, 64);
      l_run += rs;
      #pragma unroll
      for (int sb = 0; sb < 4; sb++) {
        ushort4 pk;
        pk.x = f2bf(sc[sb][0]); pk.y = f2bf(sc[sb][1]);
        pk.z = f2bf(sc[sb][2]); pk.w = f2bf(sc[sb][3]);
        *(ushort4*)&Plds[wave][ql][sb * 16 + kg * 4] = pk;
      }
      __builtin_amdgcn_s_setprio(1);
      #pragma unroll
      for (int hf = 0; hf < 2; hf++) {
        u16x8 pf = *(const u16x8*)&Plds[wave][ql][hf * 32 + kg * 8];
        #pragma unroll
        for (int db = 0; db < 8; db++) {
          u16x8 vf = *(const u16x8*)&Vt[cur][db * 16 + ql][hf * 32 + kg * 8];
          acc[db] = mfma16(pf, vf, acc[db]);
        }
      }
      __builtin_amdgcn_s_setprio(0);
      cur ^= 1;
    }

    float linv[4];
    #pragma unroll
    for (int r = 0; r < 4; r++)
      linv[r] = 1.f / __shfl(l_run, (lane & 48) | (kg * 4 + r), 64);
    #pragma unroll
    for (int db = 0; db < 8; db++) {
      int d = db * 16 + ql;
      #pragma unroll
      for (int r = 0; r < 4; r++) {
        int q = qw + kg * 4 + r;
        int col = (h * 128 + d) ^ ((q & 7) << 3);
        out[(size_t)q * 4096 + col] = f2bf(acc[db][r] * linv[r]);
      }
    }
  }
}

// ---------------- launcher ----------------
extern "C" void kernel_launch(void* const* d_in, const int* in_sizes, int n_in,
                              void* d_out, int out_size, void* d_ws, size_t ws_size,
                              hipStream_t stream) {
  const float* x  = (const float*)d_in[0];
  const float* Wq = (const float*)d_in[1];
  const float* Wk = (const float*)d_in[2];
  const float* Wv = (const float*)d_in[3];
  const float* Wo = (const float*)d_in[4];
  const int* start = (const int*)d_in[5];

  const int L = 2048, HID = 4096, NH = 32, NKV = 8;
  const int NQ = 4096, NKVD = 1024, NF = 6144;

  char* ws = (char*)d_ws;
  size_t off = 0;
  auto alloc = [&](size_t bytes) {
    void* p = ws + off;
    off += (bytes + 255) & ~(size_t)255;
    return p;
  };
  u16* x_b   = (u16*)alloc((size_t)L * HID * 2);
  // Wq_t, Wk_t, Wv_t MUST be contiguous (fused GEMM reads them as one 6144-row Bt).
  u16* Wq_t  = (u16*)alloc((size_t)NQ * HID * 2);
  u16* Wk_t  = (u16*)alloc((size_t)NKVD * HID * 2);
  u16* Wv_t  = (u16*)alloc((size_t)NKVD * HID * 2);
  u16* Wo_t  = (u16*)alloc((size_t)HID * NQ * 2);
  u16* q_r   = (u16*)alloc((size_t)L * NQ * 2);
  u16* k_r   = (u16*)alloc((size_t)L * NKVD * 2);
  float2* tab = (float2*)alloc((size_t)L * 64 * sizeof(float2));
  u16* qkv_b  = (u16*)d_out;   // fused QKV output; fully rewritten by out-proj
  u16* attn_b = Wq_t;          // reuse Wq^T region after the fused GEMM

  const float qscale = 0.08838834764831845f * 1.4426950408889634f;  // 1/sqrt(128)*log2(e)

  // conversions / transposes / table (all GEMM inputs pre-swizzled)
  cvt_f32_bf16_swz<<<(L * HID / 8 + 255) / 256, 256, 0, stream>>>(x, x_b, L * HID / 8);
  transpose_cvt<<<dim3(HID / 32, NQ / 32), 256, 0, stream>>>(Wq, Wq_t, HID, NQ);
  transpose_cvt<<<dim3(HID / 32, NKVD / 32), 256, 0, stream>>>(Wk, Wk_t, HID, NKVD);
  transpose_cvt<<<dim3(HID / 32, NKVD / 32), 256, 0, stream>>>(Wv, Wv_t, HID, NKVD);
  transpose_cvt<<<dim3(NQ / 32, HID / 32), 256, 0, stream>>>(Wo, Wo_t, NQ, HID);
  rope_table_k<<<(L * 64 + 255) / 256, 256, 0, stream>>>(tab, start, L);

  // fused QKV projection: [2048][6144] bf16 (8-phase, 256x256 tiles, grid 192)
  gemm8p<256, true><<<192, 512, 0, stream>>>(x_b, Wq_t, nullptr, qkv_b, NF, HID, 8);

  // RoPE: Q (scaled, log2e folded, linear) and K (unscaled, chunk-swizzled)
  rope_apply_b<<<(L * NH * 8 + 255) / 256, 256, 0, stream>>>(qkv_b, NF, 0, q_r, tab, L * NH * 8, NH, qscale, 0);
  rope_apply_b<<<(L * NKV * 8 + 255) / 256, 256, 0, stream>>>(qkv_b, NF, NQ, k_r, tab, L * NKV * 8, NKV, 1.0f, 1);

  // attention
  attn_k<<<dim3(16, NH), 256, 0, stream>>>(q_r, k_r, qkv_b, attn_b);

  // output projection: 8-phase, 256x128 tiles, grid 256 (1 block/CU)
  gemm8p<128, false><<<256, 512, 0, stream>>>(attn_b, Wo_t, (float*)d_out, nullptr, HID, NQ, 8);
}

// Round 9
// 362.558 us; speedup vs baseline: 1.5904x; 1.0377x over previous
//
#include <hip/hip_runtime.h>

typedef unsigned short u16;
typedef float f32x4 __attribute__((ext_vector_type(4)));
typedef __bf16 bf16x8 __attribute__((ext_vector_type(8)));
typedef u16 u16x8 __attribute__((ext_vector_type(8)));

#define VMCNT(n) asm volatile("s_waitcnt vmcnt(" #n ")" ::: "memory")

static __device__ __forceinline__ u16 f2bf(float f) {
  union { float f; unsigned u; } v; v.f = f;
  unsigned r = v.u + 0x7fffu + ((v.u >> 16) & 1u);  // RNE
  return (u16)(r >> 16);
}
static __device__ __forceinline__ float bf2f(u16 x) {
  union { unsigned u; float f; } v; v.u = (unsigned)x << 16; return v.f;
}

static __device__ __forceinline__ f32x4 mfma16(u16x8 a, u16x8 b, f32x4 c) {
  return __builtin_amdgcn_mfma_f32_16x16x32_bf16(
      __builtin_bit_cast(bf16x8, a), __builtin_bit_cast(bf16x8, b), c, 0, 0, 0);
}

static __device__ __forceinline__ void load_lds16(const void* g, void* l) {
  __builtin_amdgcn_global_load_lds(
      (const __attribute__((address_space(1))) void*)g,
      (__attribute__((address_space(3))) void*)l, 16, 0, 0);
}

// ---------------- f32 -> bf16, GEMM-A pre-swizzled (chunk c of row r at c^(r&7)) ----
__global__ void cvt_f32_bf16_swz(const float* __restrict__ in, u16* __restrict__ out, int n8) {
  int i = blockIdx.x * blockDim.x + threadIdx.x;
  if (i >= n8) return;
  int row = i >> 9;
  int j = i & 511;
  int jp = (j & ~7) | ((j & 7) ^ (row & 7));
  const float* src = in + (size_t)i * 8;
  u16x8 o;
  #pragma unroll
  for (int e = 0; e < 8; e++) o[e] = f2bf(src[e]);
  *(u16x8*)(out + ((size_t)row << 12) + jp * 8) = o;
}

// ------- transpose + convert: W[K][N] f32 -> Wt[N][K] bf16, pre-swizzled rows -------
// 128k x 32n tiles; float4 loads, u16x8 stores (256B contiguous per output row).
__global__ __launch_bounds__(256)
void transpose_cvt(const float* __restrict__ W, u16* __restrict__ Wt, int K, int N) {
  __shared__ float tile[128][33];
  const int k0 = blockIdx.x * 128, n0 = blockIdx.y * 32;
  const int tr = threadIdx.x >> 3;         // 0..31
  const int tc4 = (threadIdx.x & 7) * 4;   // 0..28
  #pragma unroll
  for (int it = 0; it < 4; it++) {
    int kl = it * 32 + tr;
    float4 v = *(const float4*)&W[(size_t)(k0 + kl) * N + n0 + tc4];
    tile[kl][tc4] = v.x; tile[kl][tc4 + 1] = v.y;
    tile[kl][tc4 + 2] = v.z; tile[kl][tc4 + 3] = v.w;
  }
  __syncthreads();
  const int nl = threadIdx.x >> 4;         // 0..15
  const int dch = threadIdx.x & 15;        // dest 16B chunk 0..15
  #pragma unroll
  for (int it = 0; it < 2; it++) {
    int n = n0 + it * 16 + nl;
    int sch = (dch & 8) | ((dch & 7) ^ (n & 7));  // source chunk (involution)
    u16x8 o;
    #pragma unroll
    for (int e = 0; e < 8; e++) o[e] = f2bf(tile[sch * 8 + e][it * 16 + nl]);
    *(u16x8*)&Wt[(size_t)n * K + k0 + dch * 8] = o;
  }
}

// ---------------- RoPE cos/sin table: [L][64] float2 ----------------
__global__ void rope_table_k(float2* __restrict__ tab, const int* __restrict__ start, int L) {
  int i = blockIdx.x * blockDim.x + threadIdx.x;
  if (i >= L * 64) return;
  int p = i >> 6, j = i & 63;
  float inv = powf(10000.0f, -(float)j / 64.0f);
  float ang = (float)(p + start[0]) * inv;
  tab[i] = make_float2(cosf(ang), sinf(ang));
}

// ---------------- RoPE apply (bf16 in, strided) -> bf16 [L][H][128], * scale ----------
__global__ void rope_apply_b(const u16* __restrict__ in, int istride, int icol,
                             u16* __restrict__ outp, const float2* __restrict__ tab,
                             int total, int H, float scale, int swz) {
  int i = blockIdx.x * blockDim.x + threadIdx.x;  // total = L*H*8
  if (i >= total) return;
  int j8 = (i & 7) * 8;
  int h = (i >> 3) % H;
  int p = i / (8 * H);
  const u16* base = in + (size_t)p * istride + icol + h * 128;
  u16x8 a = *(const u16x8*)(base + j8);
  u16x8 b = *(const u16x8*)(base + j8 + 64);
  u16x8 o1, o2;
  #pragma unroll
  for (int e = 0; e < 8; e++) {
    float2 cs = tab[p * 64 + j8 + e];
    float av = bf2f(a[e]), bv = bf2f(b[e]);
    o1[e] = f2bf((av * cs.x - bv * cs.y) * scale);
    o2[e] = f2bf((av * cs.y + bv * cs.x) * scale);
  }
  int c1 = i & 7;
  int cs1 = swz ? (c1 ^ (p & 7)) : c1;
  u16* ob = outp + ((size_t)p * H + h) * 128 + cs1 * 8;
  *(u16x8*)ob = o1;
  *(u16x8*)(ob + 64) = o2;
}

// ======== 8-phase GEMM: C = A[M][K] @ Bt[N][K]; BM=256, BK=64, 512 thr (2x4 waves) ==
// Quadrant/stage schedule as R7 (stage-to-read distance 3-4 phases, dbuf).
// SOUND GATING (fixes R8 race): at the END of every phase, BEFORE barrier-1, each
// wave waits vmcnt(issues(p)+issues(p-1)) -> only loads issued in this and the
// previous phase remain outstanding. Every read at phase p consumes data staged
// >=3 phases earlier, so the STAGING wave's own gate + a shared barrier strictly
// precede the read (vmcnt is per-wave; in-order retirement). Prologue gets the
// same gate + barrier. Tail (nothing staged at p>=4): vmcnt(2)@p4, vmcnt(0)@p5.
// lgkmcnt(0) sits AFTER barrier-1 (ds drain absorbed in barrier wait), with a
// sched_barrier fence (rule #18).
template<int BN, bool OUT_BF16>
__global__ __launch_bounds__(512, 2)
void gemm8p(const u16* __restrict__ A, const u16* __restrict__ Bt,
            float* __restrict__ Cf, u16* __restrict__ Cb, int N, int K, int gm) {
  constexpr int N_REP = BN / 64;
  constexpr int NHALF = N_REP / 2 > 0 ? N_REP / 2 : 1;
  constexpr int STR = 16 * NHALF;
  constexpr int BJP = (BN == 256) ? 2 : 1;
  __shared__ alignas(16) u16 As[2][256 * 64];
  __shared__ alignas(16) u16 Bs[2][BN * 64];
  const int tid = threadIdx.x;
  const int lane = tid & 63;
  const int wid = tid >> 6;
  const int ql = lane & 15, kg = lane >> 4;
  const int wr = wid >> 2, wcn = wid & 3;

  const int nb = gridDim.x;
  const int b = blockIdx.x;
  const int swz = (b & 7) * (nb >> 3) + (b >> 3);
  const int m0 = (swz % gm) * 256;
  const int n0 = (swz / gm) * BN;

  const int srow = tid >> 3, schk = tid & 7;
  const u16* abase = A + (size_t)(m0 + srow) * K + schk * 8;
  const u16* bbase = Bt + (size_t)n0 * K + schk * 8;

  auto stageA = [&](int buf, int t, int qa) {
    load_lds16(abase + (size_t)(qa * 64) * K + t * 64,
               &As[buf][((qa * 64 + srow) * 8 + schk) * 8]);
  };
  auto stageB = [&](int buf, int t, int n2, int jp) {
    int j = jp * (64 / STR) + srow / STR;
    int r = srow % STR;
    int g = j * (2 * STR) + n2 * STR + r;
    load_lds16(bbase + (size_t)g * K + t * 64,
               &Bs[buf][((n2 * (BN / 2) + jp * 64 + srow) * 8 + schk) * 8]);
  };

  f32x4 acc[8][N_REP] = {};
  u16x8 af[4][2];
  u16x8 bfr[2][NHALF][2];
  const int NT = K / 64;

  // prologue: tile 0 -> buf0, then SOUND gate + barrier (covers phase-0 reads;
  // later prologue loads are retired by the phase-0/1 end gates).
  stageA(0, 0, 0); stageA(0, 0, 2);
  #pragma unroll
  for (int jp = 0; jp < BJP; jp++) stageB(0, 0, 0, jp);
  #pragma unroll
  for (int jp = 0; jp < BJP; jp++) stageB(0, 0, 1, jp);
  stageA(0, 0, 1); stageA(0, 0, 3);
  if constexpr (BN == 256) VMCNT(4); else VMCNT(3);
  __builtin_amdgcn_sched_barrier(0);
  __builtin_amdgcn_s_barrier();

  #pragma unroll 1
  for (int i = 0; i < NT / 2; i++) {
    const bool tail = (i == NT / 2 - 1);
    #pragma unroll
    for (int p = 0; p < 8; p++) {
      const int q = p & 3;
      const int m = q >> 1, n2 = q & 1;
      const int cbuf = (p < 4) ? 0 : 1;
      // ds_reads for this quadrant (data published by the previous barrier)
      if (q == 0 || q == 2) {
        #pragma unroll
        for (int mi = 0; mi < 4; mi++)
          #pragma unroll
          for (int kk = 0; kk < 2; kk++) {
            int row = wr * 128 + m * 64 + mi * 16 + ql;
            int ch = ((kk << 2) | kg) ^ (ql & 7);
            af[mi][kk] = *(const u16x8*)&As[cbuf][(row * 8 + ch) * 8];
          }
      }
      if (q == 0 || q == 1) {
        #pragma unroll
        for (int ni = 0; ni < NHALF; ni++)
          #pragma unroll
          for (int kk = 0; kk < 2; kk++) {
            int R = q * (BN / 2) + wcn * STR + ni * 16 + ql;
            int ch = ((kk << 2) | kg) ^ (ql & 7);
            bfr[q][ni][kk] = *(const u16x8*)&Bs[cbuf][(R * 8 + ch) * 8];
          }
      }
      // stage rounds (phases 0-3: tile 2i+1 -> buf1; 4-7: tile 2i+2 -> buf0)
      const int st = 2 * i + 1 + (p >= 4 ? 1 : 0);
      const int sbuf = st & 1;
      if (st < NT) {
        if (q == 0) { stageA(sbuf, st, 0); stageA(sbuf, st, 2); }
        else if (q == 1) {
          #pragma unroll
          for (int jp = 0; jp < BJP; jp++) stageB(sbuf, st, 0, jp);
        } else if (q == 2) {
          #pragma unroll
          for (int jp = 0; jp < BJP; jp++) stageB(sbuf, st, 1, jp);
        } else { stageA(sbuf, st, 1); stageA(sbuf, st, 3); }
      }
      // END-OF-PHASE sound gate: vmcnt(issues(p)+issues(p-1))
      if (!tail || p < 4) {
        if constexpr (BN == 256) {
          VMCNT(4);
        } else {
          if (q == 0) VMCNT(4);
          else if (q == 1) VMCNT(3);
          else if (q == 2) VMCNT(2);
          else VMCNT(3);
        }
      } else {
        if (p == 4) VMCNT(2);
        else if (p == 5) VMCNT(0);
      }
      __builtin_amdgcn_sched_barrier(0);
      __builtin_amdgcn_s_barrier();
      asm volatile("s_waitcnt lgkmcnt(0)" ::: "memory");
      __builtin_amdgcn_sched_barrier(0);
      __builtin_amdgcn_s_setprio(1);
      #pragma unroll
      for (int mi = 0; mi < 4; mi++)
        #pragma unroll
        for (int ni = 0; ni < NHALF; ni++)
          #pragma unroll
          for (int kk = 0; kk < 2; kk++)
            acc[m * 4 + mi][n2 * NHALF + ni] =
                mfma16(af[mi][kk], bfr[n2][ni][kk], acc[m * 4 + mi][n2 * NHALF + ni]);
      __builtin_amdgcn_s_setprio(0);
      __builtin_amdgcn_sched_barrier(0);
      __builtin_amdgcn_s_barrier();
    }
  }

  #pragma unroll
  for (int mi = 0; mi < 8; mi++) {
    #pragma unroll
    for (int ni = 0; ni < N_REP; ni++) {
      int row0 = m0 + wr * 128 + mi * 16 + kg * 4;
      int col = n0 + wcn * (16 * N_REP) + ni * 16 + ql;
      #pragma unroll
      for (int r = 0; r < 4; r++) {
        if constexpr (OUT_BF16)
          Cb[(size_t)(row0 + r) * N + col] = f2bf(acc[mi][ni][r]);
        else
          Cf[(size_t)(row0 + r) * N + col] = acc[mi][ni][r];
      }
    }
  }
}

// ---------------- flash attention, causal, GQA (g=4) ----------------
// (unchanged from R7)
__global__ __launch_bounds__(256, 2)
void attn_k(const u16* __restrict__ qr, const u16* __restrict__ kr,
            const u16* __restrict__ qkv, u16* __restrict__ out) {
  __shared__ alignas(16) u16 Kls[2][64 * 128];
  __shared__ alignas(16) u16 Vt[2][128][72];
  __shared__ alignas(16) u16 Plds[4][16][72];
  const int tid = threadIdx.x;
  const int lane = tid & 63, wave = tid >> 6;
  const int ql = lane & 15, kg = lane >> 4;
  const int h = blockIdx.y, hk = h >> 2;

  const int sl4 = (tid & 15) * 4;
  const int d0s = (tid >> 4) * 8;
  const u16* vbase = qkv + 5120 + (size_t)hk * 128 + d0s;
  const int krow_s = tid >> 4, kcol_s = (tid & 15) * 8;
  const u16* kbase = kr + (size_t)hk * 128 + (size_t)krow_s * 1024 + kcol_s;

  int cur = 0;
  #pragma unroll 1
  for (int half_idx = 0; half_idx < 2; half_idx++) {
    const int tile = half_idx ? (31 - (int)blockIdx.x) : (int)blockIdx.x;
    const int q0 = tile * 64;
    const int qw = q0 + wave * 16;
    const int nsteps = tile + 1;

    u16x8 qf[4];
    const u16* qbase = qr + ((size_t)(qw + ql) * 32 + h) * 128;
    #pragma unroll
    for (int kk = 0; kk < 4; kk++)
      qf[kk] = *(const u16x8*)(qbase + kk * 32 + kg * 8);

    f32x4 acc[8] = {};
    float m_run = -3e38f, l_run = 0.f;

    __syncthreads();
    cur = 0;
    #pragma unroll
    for (int r = 0; r < 4; r++)
      load_lds16(kbase + (size_t)r * 16 * 1024, &Kls[0][(r * 256 + tid) * 8]);
    u16x8 vreg[4];
    #pragma unroll
    for (int j = 0; j < 4; j++)
      vreg[j] = *(const u16x8*)(vbase + (size_t)(sl4 + j) * 6144);

    #pragma unroll 1
    for (int t = 0; t < nsteps; t++) {
      const int s0 = t * 64;
      #pragma unroll
      for (int e = 0; e < 8; e++) {
        ushort4 w;
        w.x = vreg[0][e]; w.y = vreg[1][e]; w.z = vreg[2][e]; w.w = vreg[3][e];
        *(ushort4*)&Vt[cur][d0s + e][sl4] = w;
      }
      __syncthreads();  // the ONLY barrier per step
      if (t + 1 < nsteps) {
        const u16* kn = kbase + (size_t)(s0 + 64) * 1024;
        #pragma unroll
        for (int r = 0; r < 4; r++)
          load_lds16(kn + (size_t)r * 16 * 1024, &Kls[cur ^ 1][(r * 256 + tid) * 8]);
        #pragma unroll
        for (int j = 0; j < 4; j++)
          vreg[j] = *(const u16x8*)(vbase + (size_t)(s0 + 64 + sl4 + j) * 6144);
      }
      f32x4 sc[4] = {};
      __builtin_amdgcn_s_setprio(1);
      #pragma unroll
      for (int sb = 0; sb < 4; sb++) {
        const u16* krow = &Kls[cur][(sb * 16 + ql) * 128];
        #pragma unroll
        for (int kk = 0; kk < 4; kk++) {
          u16x8 kf = *(const u16x8*)(krow + (((kk * 4 + kg) ^ (ql & 7)) * 8));
          sc[sb] = mfma16(kf, qf[kk], sc[sb]);
        }
      }
      __builtin_amdgcn_s_setprio(0);
      const int qg = qw + ql;
      float mt = -3e38f;
      #pragma unroll
      for (int sb = 0; sb < 4; sb++)
        #pragma unroll
        for (int r = 0; r < 4; r++) {
          int s = s0 + sb * 16 + kg * 4 + r;
          float v = (s > qg) ? -3e38f : sc[sb][r];
          sc[sb][r] = v;
          mt = fmaxf(mt, v);
        }
      mt = fmaxf(mt, __shfl_xor(mt, 16, 64));
      mt = fmaxf(mt, __shfl_xor(mt, 32, 64));
      if (!__all(mt - m_run <= 11.5f)) {
        float m_new = fmaxf(m_run, mt);
        float fco = exp2f(m_run - m_new);
        float fr[4];
        #pragma unroll
        for (int r = 0; r < 4; r++) fr[r] = __shfl(fco, (lane & 48) | (kg * 4 + r), 64);
        #pragma unroll
        for (int db = 0; db < 8; db++)
          #pragma unroll
          for (int r = 0; r < 4; r++) acc[db][r] *= fr[r];
        l_run *= fco;
        m_run = m_new;
      }
      float rs = 0.f;
      #pragma unroll
      for (int sb = 0; sb < 4; sb++)
        #pragma unroll
        for (int r = 0; r < 4; r++) {
          float e = exp2f(sc[sb][r] - m_run);
          sc[sb][r] = e;
          rs += e;
        }
      rs += __shfl_xor(rs, 16, 64);
      rs += __shfl_xor(rs, 32, 64);
      l_run += rs;
      #pragma unroll
      for (int sb = 0; sb < 4; sb++) {
        ushort4 pk;
        pk.x = f2bf(sc[sb][0]); pk.y = f2bf(sc[sb][1]);
        pk.z = f2bf(sc[sb][2]); pk.w = f2bf(sc[sb][3]);
        *(ushort4*)&Plds[wave][ql][sb * 16 + kg * 4] = pk;
      }
      __builtin_amdgcn_s_setprio(1);
      #pragma unroll
      for (int hf = 0; hf < 2; hf++) {
        u16x8 pf = *(const u16x8*)&Plds[wave][ql][hf * 32 + kg * 8];
        #pragma unroll
        for (int db = 0; db < 8; db++) {
          u16x8 vf = *(const u16x8*)&Vt[cur][db * 16 + ql][hf * 32 + kg * 8];
          acc[db] = mfma16(pf, vf, acc[db]);
        }
      }
      __builtin_amdgcn_s_setprio(0);
      cur ^= 1;
    }

    float linv[4];
    #pragma unroll
    for (int r = 0; r < 4; r++)
      linv[r] = 1.f / __shfl(l_run, (lane & 48) | (kg * 4 + r), 64);
    #pragma unroll
    for (int db = 0; db < 8; db++) {
      int d = db * 16 + ql;
      #pragma unroll
      for (int r = 0; r < 4; r++) {
        int q = qw + kg * 4 + r;
        int col = (h * 128 + d) ^ ((q & 7) << 3);
        out[(size_t)q * 4096 + col] = f2bf(acc[db][r] * linv[r]);
      }
    }
  }
}

// ---------------- launcher ----------------
extern "C" void kernel_launch(void* const* d_in, const int* in_sizes, int n_in,
                              void* d_out, int out_size, void* d_ws, size_t ws_size,
                              hipStream_t stream) {
  const float* x  = (const float*)d_in[0];
  const float* Wq = (const float*)d_in[1];
  const float* Wk = (const float*)d_in[2];
  const float* Wv = (const float*)d_in[3];
  const float* Wo = (const float*)d_in[4];
  const int* start = (const int*)d_in[5];

  const int L = 2048, HID = 4096, NH = 32, NKV = 8;
  const int NQ = 4096, NKVD = 1024, NF = 6144;

  char* ws = (char*)d_ws;
  size_t off = 0;
  auto alloc = [&](size_t bytes) {
    void* p = ws + off;
    off += (bytes + 255) & ~(size_t)255;
    return p;
  };
  u16* x_b   = (u16*)alloc((size_t)L * HID * 2);
  // Wq_t, Wk_t, Wv_t MUST be contiguous (fused GEMM reads them as one 6144-row Bt).
  u16* Wq_t  = (u16*)alloc((size_t)NQ * HID * 2);
  u16* Wk_t  = (u16*)alloc((size_t)NKVD * HID * 2);
  u16* Wv_t  = (u16*)alloc((size_t)NKVD * HID * 2);
  u16* Wo_t  = (u16*)alloc((size_t)HID * NQ * 2);
  u16* q_r   = (u16*)alloc((size_t)L * NQ * 2);
  u16* k_r   = (u16*)alloc((size_t)L * NKVD * 2);
  float2* tab = (float2*)alloc((size_t)L * 64 * sizeof(float2));
  u16* qkv_b  = (u16*)d_out;   // fused QKV output; fully rewritten by out-proj
  u16* attn_b = Wq_t;          // reuse Wq^T region after the fused GEMM

  const float qscale = 0.08838834764831845f * 1.4426950408889634f;  // 1/sqrt(128)*log2(e)

  // conversions / transposes / table (all GEMM inputs pre-swizzled)
  cvt_f32_bf16_swz<<<(L * HID / 8 + 255) / 256, 256, 0, stream>>>(x, x_b, L * HID / 8);
  transpose_cvt<<<dim3(HID / 128, NQ / 32), 256, 0, stream>>>(Wq, Wq_t, HID, NQ);
  transpose_cvt<<<dim3(HID / 128, NKVD / 32), 256, 0, stream>>>(Wk, Wk_t, HID, NKVD);
  transpose_cvt<<<dim3(HID / 128, NKVD / 32), 256, 0, stream>>>(Wv, Wv_t, HID, NKVD);
  transpose_cvt<<<dim3(NQ / 128, HID / 32), 256, 0, stream>>>(Wo, Wo_t, NQ, HID);
  rope_table_k<<<(L * 64 + 255) / 256, 256, 0, stream>>>(tab, start, L);

  // fused QKV projection: [2048][6144] bf16 (8-phase, 256x256 tiles, grid 192)
  gemm8p<256, true><<<192, 512, 0, stream>>>(x_b, Wq_t, nullptr, qkv_b, NF, HID, 8);

  // RoPE: Q (scaled, log2e folded, linear) and K (unscaled, chunk-swizzled)
  rope_apply_b<<<(L * NH * 8 + 255) / 256, 256, 0, stream>>>(qkv_b, NF, 0, q_r, tab, L * NH * 8, NH, qscale, 0);
  rope_apply_b<<<(L * NKV * 8 + 255) / 256, 256, 0, stream>>>(qkv_b, NF, NQ, k_r, tab, L * NKV * 8, NKV, 1.0f, 1);

  // attention
  attn_k<<<dim3(16, NH), 256, 0, stream>>>(q_r, k_r, qkv_b, attn_b);

  // output projection: 8-phase, 256x128 tiles, grid 256 (1 block/CU)
  gemm8p<128, false><<<256, 512, 0, stream>>>(attn_b, Wo_t, (float*)d_out, nullptr, HID, NQ, 8);
}